// Round 11
// baseline (161.536 us; speedup 1.0000x reference)
//
#include <hip/hip_runtime.h>
#include <hip/hip_bf16.h>
#include <math.h>

#define NB 16
#define NS 1024
#define NM 256
#define NH 8
#define NDK 32
#define NL 2

typedef __attribute__((ext_vector_type(4))) float f32x4;
typedef __attribute__((ext_vector_type(8))) short bf16x8;
typedef __attribute__((ext_vector_type(4))) short bf16x4u;

#if __has_builtin(__builtin_amdgcn_exp2f)
#define EXP2F(x) __builtin_amdgcn_exp2f(x)
#else
#define EXP2F(x) exp2f(x)
#endif

__device__ __forceinline__ unsigned short f2bf(float f) {
  unsigned int u = __builtin_bit_cast(unsigned int, f);
  unsigned int r = u + 0x7fffu + ((u >> 16) & 1u);
  return (unsigned short)(r >> 16);
}
__device__ __forceinline__ float bf2f(unsigned short h) {
  unsigned int u = ((unsigned int)h) << 16;
  return __builtin_bit_cast(float, u);
}

// ---------------------------------------------------------------------------
// Pack one int32 0/1 array into a bitmask via ballot. inv=1 packs (v==0).
// Wave handles 256 elements: lane loads src[eb + c*64 + lane] (256B/wave-load,
// 4 independent loads/thread). One ballot = 64 consecutive bits.
__global__ __launch_bounds__(256) void packbits_kernel(
    const int* __restrict__ src, unsigned long long* __restrict__ dst, int inv)
{
  size_t wid = (size_t)blockIdx.x * 4 + (threadIdx.x >> 6);
  int lane = threadIdx.x & 63;
  size_t eb = wid * 256;
  unsigned long long bal[4];
#pragma unroll
  for (int c = 0; c < 4; ++c) {
    int v = src[eb + c * 64 + lane];
    bal[c] = __ballot(((v != 0) ? 1 : 0) ^ inv);
  }
  if (lane == 0) {
    unsigned long long* d = dst + wid * 4;
    d[0] = bal[0]; d[1] = bal[1]; d[2] = bal[2]; d[3] = bal[3];
  }
}

// ---------------------------------------------------------------------------
// pkc |= pks (element-wise over the packed words).
__global__ __launch_bounds__(256) void maskcomb_kernel(
    unsigned int* __restrict__ pkc, const unsigned int* __restrict__ pks)
{
  int t = blockIdx.x * 256 + threadIdx.x;
  uint4 a = ((uint4*)pkc)[t];
  uint4 s = ((const uint4*)pks)[t];
  a.x |= s.x; a.y |= s.y; a.z |= s.z; a.w |= s.w;
  ((uint4*)pkc)[t] = a;
}

// ---------------------------------------------------------------------------
// Projection GEMM -> Pt[b][h][d][s] (bf16), 64x64 tile, 4 waves.
__global__ __launch_bounds__(256) void proj_kernel(
    const float* __restrict__ x,        // (B*S, M)
    const float* __restrict__ pw,       // (H, M, DK) this layer
    const float* __restrict__ pb,       // (H*DK)
    unsigned short* __restrict__ Pt)    // (B,H,DK,S)
{
  __shared__ unsigned short As[64][40];
  __shared__ unsigned short Bs[64][40];

  int ct = blockIdx.x;
  int rt = blockIdx.y;
  int t = threadIdx.x;
  int w = t >> 6, lane = t & 63;
  int il = lane & 15, g4 = lane >> 4;
  int wi = w >> 1, wc = w & 1;

  f32x4 acc[2][2] = {};

  int arow = t >> 2, akoff = (t & 3) * 8;
  int bcol = t & 63, bk0 = (t >> 6) * 8;
  int hd = ct * 64 + bcol;
  int h = hd >> 5, d = hd & 31;

  for (int k0 = 0; k0 < NM; k0 += 32) {
    const float* xp = x + (size_t)(rt * 64 + arow) * NM + k0 + akoff;
    f32x4 v0 = *(const f32x4*)xp;
    f32x4 v1 = *(const f32x4*)(xp + 4);
    bf16x8 av;
    av[0] = f2bf(v0[0]); av[1] = f2bf(v0[1]); av[2] = f2bf(v0[2]); av[3] = f2bf(v0[3]);
    av[4] = f2bf(v1[0]); av[5] = f2bf(v1[1]); av[6] = f2bf(v1[2]); av[7] = f2bf(v1[3]);
    *(bf16x8*)&As[arow][akoff] = av;
    const float* wp = pw + (size_t)h * NM * NDK + (size_t)(k0 + bk0) * NDK + d;
    bf16x8 bv;
#pragma unroll
    for (int q = 0; q < 8; ++q) bv[q] = f2bf(wp[q * NDK]);
    *(bf16x8*)&Bs[bcol][bk0] = bv;
    __syncthreads();

    bf16x8 af0 = *(bf16x8*)&As[wi * 32 + il][g4 * 8];
    bf16x8 af1 = *(bf16x8*)&As[wi * 32 + 16 + il][g4 * 8];
    bf16x8 bf0 = *(bf16x8*)&Bs[wc * 32 + il][g4 * 8];
    bf16x8 bf1 = *(bf16x8*)&Bs[wc * 32 + 16 + il][g4 * 8];
    acc[0][0] = __builtin_amdgcn_mfma_f32_16x16x32_bf16(af0, bf0, acc[0][0], 0, 0, 0);
    acc[0][1] = __builtin_amdgcn_mfma_f32_16x16x32_bf16(af0, bf1, acc[0][1], 0, 0, 0);
    acc[1][0] = __builtin_amdgcn_mfma_f32_16x16x32_bf16(af1, bf0, acc[1][0], 0, 0, 0);
    acc[1][1] = __builtin_amdgcn_mfma_f32_16x16x32_bf16(af1, bf1, acc[1][1], 0, 0, 0);
    __syncthreads();
  }

#pragma unroll
  for (int ih = 0; ih < 2; ++ih) {
#pragma unroll
    for (int dh = 0; dh < 2; ++dh) {
      int colhd = ct * 64 + wc * 32 + dh * 16 + il;
      int hh = colhd >> 5, dd = colhd & 31;
      float bias = pb[colhd];
      int r0 = rt * 64 + wi * 32 + ih * 16 + g4 * 4;
      int bb = r0 >> 10, ss = r0 & 1023;
      f32x4 c = acc[ih][dh];
      unsigned short ov[4];
#pragma unroll
      for (int e = 0; e < 4; ++e) ov[e] = f2bf(c[e] + bias);
      size_t idx = ((size_t)(bb * NH + hh) * NDK + dd) * NS + ss;
      *(bf16x4u*)(Pt + idx) = *(bf16x4u*)ov;
    }
  }
}

// ---------------------------------------------------------------------------
// s1 raw (log2e-scaled); s2 factored: s2p = exp2(s2L), s2n = exp2(0.2*s2L).
__global__ __launch_bounds__(256) void s_kernel(
    const unsigned short* __restrict__ Pt,
    const float* __restrict__ aw,   // 64 floats this layer
    const float* __restrict__ abp,  // attn_b + l
    float* __restrict__ s1o, float* __restrict__ s2po, float* __restrict__ s2no)
{
  const float LOG2E = 1.4426950408889634f;
  int t = blockIdx.x * 256 + threadIdx.x;   // (b*H+h)*S + s
  int bh = t >> 10, s = t & 1023;
  const unsigned short* p = Pt + (size_t)bh * NDK * NS + s;
  float s1 = 0.f, s2 = 0.f;
#pragma unroll
  for (int dd = 0; dd < NDK; ++dd) {
    float pv = bf2f(p[dd * NS]);
    s1 += pv * aw[dd];
    s2 += pv * aw[32 + dd];
  }
  float s2L = (s2 + abp[0]) * LOG2E;
  s2L = fminf(fmaxf(s2L, -30.f), 30.f);
  s1o[t] = s1 * LOG2E;
  s2po[t] = EXP2F(s2L);
  s2no[t] = EXP2F(0.2f * s2L);
}

// ---------------------------------------------------------------------------
// Attention with LDS-staged Pt and FACTORED exp weights:
//   score>=0: w = E1p*E2p ; score<0: w = E1n*E2n ; branch: E2p >= exp2(-s1).
// No per-element transcendentals. Block = (b, head, i-quarter), 16 waves;
// wave w owns 16 rows. Pt staged in two 32KB swizzled j-halves.
__global__ __launch_bounds__(1024, 8) void attn_kernel(
    const unsigned short* __restrict__ Pt,    // (B,H,DK,S) bf16
    const float* __restrict__ s1a,            // (B,H,S), log2e-scaled
    const float* __restrict__ s2pa,           // exp2(s2L)
    const float* __restrict__ s2na,           // exp2(0.2*s2L)
    const unsigned int* __restrict__ pkc,     // combined mask bits
    const unsigned int* __restrict__ pks,     // smask-only bits
    const int* __restrict__ typep,
    int layer,
    float* __restrict__ co)                   // (B,S,M) f32 concat out
{
  __shared__ __align__(16) unsigned short ptl[32 * 512];  // 32KB, swizzled
  __shared__ float s2pl[1024];                            // 4KB
  __shared__ float s2nl[1024];                            // 4KB

  // XCD chunk swizzle: 64 consecutive logical blocks (2 batches) per XCD.
  int orig = blockIdx.x;
  int lb = (orig & 7) * 64 + (orig >> 3);
  int iq = lb & 3, bh = lb >> 2;
  int b = bh >> 3, h = bh & 7;

  int t = threadIdx.x, w = t >> 6, lane = t & 63;
  int il = lane & 15, g4 = lane >> 4;
  int xorv = (il & 7) << 4;

  const unsigned char* pkb =
      (const unsigned char*)((typep[0] == 1 && layer > 0) ? pks : pkc);
  const unsigned short* ptg = Pt + (size_t)bh * NDK * NS;

  bf16x8 ones;
#pragma unroll
  for (int e = 0; e < 8; ++e) ones[e] = (short)0x3F80;     // bf16 1.0

  int rbase = iq * 256 + w * 16;
  float s1L = s1a[(size_t)bh * NS + rbase + il];
  s1L = fminf(fmaxf(s1L, -30.f), 30.f);
  float e1p = EXP2F(s1L);
  float e1n = EXP2F(0.2f * s1L);
  float rcp1p = EXP2F(-s1L);
  const unsigned char* mrow = pkb + (((size_t)(b * NS + rbase + il) * NS) >> 3);

  f32x4 acc0 = {}, acc1 = {}, accd = {};

  for (int jh = 0; jh < 2; ++jh) {
    __syncthreads();
    // stage Pt half-slab (32 rows x 512 cols bf16 = 32KB), swizzled
    {
      const char* srcb = (const char*)ptg;
#pragma unroll
      for (int q = 0; q < 2; ++q) {
        int pos = q * 16384 + t * 16;         // 0..32767
        int r = pos >> 10;                    // row 0..31
        int incol = pos & 1023;               // byte within half-row
        uint4 v = *(const uint4*)(srcb + r * 2048 + jh * 1024 + incol);
        *(uint4*)((char*)ptl + r * 1024 + (incol ^ ((r & 7) << 4))) = v;
      }
      if (jh == 0) {
        if (t < 256)
          ((f32x4*)s2pl)[t] = *(const f32x4*)(s2pa + (size_t)bh * NS + t * 4);
        else if (t < 512)
          ((f32x4*)s2nl)[t - 256] =
              *(const f32x4*)(s2na + (size_t)bh * NS + (t - 256) * 4);
      }
    }
    __syncthreads();

    for (int jg = 0; jg < 512; jg += 128) {
      uint4 mk = *(const uint4*)(mrow + ((jh * 512 + jg) >> 3));  // 128 j-bits
#pragma unroll
      for (int s = 0; s < 4; ++s) {
        unsigned int mword = (&mk.x)[s];
        unsigned int mb = (mword >> (g4 * 8)) & 0xFFu;
        int jl = jg + s * 32 + g4 * 8;                    // local col in half
        int coff = (jl * 2) ^ xorv;
        const char* prow = (const char*)ptl + il * 1024;
        bf16x8 b0 = *(const bf16x8*)(prow + coff);
        bf16x8 b1 = *(const bf16x8*)(prow + 16 * 1024 + coff);
        int jfull = jh * 512 + jl;
        f32x4 pL = *(const f32x4*)&s2pl[jfull];
        f32x4 pH = *(const f32x4*)&s2pl[jfull + 4];
        f32x4 nL = *(const f32x4*)&s2nl[jfull];
        f32x4 nH = *(const f32x4*)&s2nl[jfull + 4];
        float e2p[8] = {pL[0], pL[1], pL[2], pL[3], pH[0], pH[1], pH[2], pH[3]};
        float e2n[8] = {nL[0], nL[1], nL[2], nL[3], nH[0], nH[1], nH[2], nH[3]};
        bf16x8 af;
#pragma unroll
        for (int e = 0; e < 8; ++e) {
          bool c = e2p[e] >= rcp1p;            // score >= 0 branch?
          float wv = (c ? e1p : e1n) * (c ? e2p[e] : e2n[e]);
          wv = (mb & (1u << e)) ? 0.f : wv;
          af[e] = (short)__bfloat16_as_ushort(__float2bfloat16(wv));
        }
        acc0 = __builtin_amdgcn_mfma_f32_16x16x32_bf16(af, b0, acc0, 0, 0, 0);
        acc1 = __builtin_amdgcn_mfma_f32_16x16x32_bf16(af, b1, acc1, 0, 0, 0);
        accd = __builtin_amdgcn_mfma_f32_16x16x32_bf16(af, ones, accd, 0, 0, 0);
      }
    }
  }

  // normalize + store concat (D layout: col=il, row=g4*4+e)
  {
    f32x4 rd;
#pragma unroll
    for (int e = 0; e < 4; ++e) rd[e] = __builtin_amdgcn_rcpf(accd[e]);
    float* cob = co + (size_t)(b * NS + rbase + g4 * 4) * NM + h * 32 + il;
#pragma unroll
    for (int e = 0; e < 4; ++e) {
      cob[(size_t)e * NM] = acc0[e] * rd[e];
      cob[(size_t)e * NM + 16] = acc1[e] * rd[e];
    }
  }
}

// ---------------------------------------------------------------------------
// Residual + LayerNorm: row r -> LN(xin[r] + co[r]) * g + b.
__global__ __launch_bounds__(256) void ln_kernel(
    const float* __restrict__ xin, const float* __restrict__ co,
    const float* __restrict__ lng, const float* __restrict__ lnb,
    float* __restrict__ xout)
{
  int row = blockIdx.x * 4 + (threadIdx.x >> 6);
  int lane = threadIdx.x & 63;
  size_t base = (size_t)row * NM + lane * 4;
  f32x4 cv = *(const f32x4*)(co + base);
  f32x4 xv = *(const f32x4*)(xin + base);
  f32x4 r;
#pragma unroll
  for (int e = 0; e < 4; ++e) r[e] = cv[e] + xv[e];
  float sm = r[0] + r[1] + r[2] + r[3];
  float sq = r[0] * r[0] + r[1] * r[1] + r[2] * r[2] + r[3] * r[3];
#pragma unroll
  for (int off = 32; off >= 1; off >>= 1) {
    sm += __shfl_xor(sm, off, 64);
    sq += __shfl_xor(sq, off, 64);
  }
  float mu = sm * (1.f / 256.f);
  float var = sq * (1.f / 256.f) - mu * mu;
  float inv = rsqrtf(var + 1e-5f);
  f32x4 gv = *(const f32x4*)(lng + lane * 4);
  f32x4 bv = *(const f32x4*)(lnb + lane * 4);
  f32x4 o;
#pragma unroll
  for (int e = 0; e < 4; ++e) o[e] = (r[e] - mu) * inv * gv[e] + bv[e];
  *(f32x4*)(xout + base) = o;
}

// ---------------------------------------------------------------------------
extern "C" void kernel_launch(void* const* d_in, const int* in_sizes, int n_in,
                              void* d_out, int out_size, void* d_ws, size_t ws_size,
                              hipStream_t stream)
{
  const int* adj = (const int*)d_in[0];
  const float* inputs = (const float*)d_in[1];
  const int* smask = (const int*)d_in[2];
  const int* typep = (const int*)d_in[3];
  const float* proj_w = (const float*)d_in[4];
  const float* proj_b = (const float*)d_in[5];
  const float* attn_w = (const float*)d_in[6];
  const float* attn_b = (const float*)d_in[7];
  const float* ln_g = (const float*)d_in[8];
  const float* ln_b = (const float*)d_in[9];
  float* out = (float*)d_out;

  char* ws = (char*)d_ws;
  unsigned int* pkc = (unsigned int*)(ws);                      // 2 MB
  unsigned int* pks = (unsigned int*)(ws + (2u << 20));         // 2 MB
  unsigned short* Pt = (unsigned short*)(ws + (4u << 20));      // 8 MB
  float* s1 = (float*)(ws + (12u << 20));                       // 512 KB
  float* s2p = (float*)(ws + (12u << 20) + (1u << 19));         // 512 KB
  float* s2n = (float*)(ws + (13u << 20));                      // 512 KB
  float* x1 = (float*)(ws + (14u << 20));                       // 16 MB
  float* co = out;   // d_out doubles as concat scratch (fully overwritten)

  // Mask packing: single-stream each (avoids lockstep dual-stream aliasing).
  packbits_kernel<<<16384, 256, 0, stream>>>(adj, (unsigned long long*)pkc, 1);
  packbits_kernel<<<16384, 256, 0, stream>>>(smask, (unsigned long long*)pks, 0);
  maskcomb_kernel<<<512, 256, 0, stream>>>(pkc, pks);

  for (int l = 0; l < NL; ++l) {
    const float* xin = (l == 0) ? inputs : x1;
    float* xout = (l == NL - 1) ? out : x1;
    proj_kernel<<<dim3(4, 256), 256, 0, stream>>>(
        xin, proj_w + (size_t)l * NH * NM * NDK, proj_b + (size_t)l * NH * NDK, Pt);
    s_kernel<<<512, 256, 0, stream>>>(Pt, attn_w + l * 64, attn_b + l, s1, s2p, s2n);
    attn_kernel<<<512, 1024, 0, stream>>>(
        Pt, s1, s2p, s2n, pkc, pks, typep, l, co);
    ln_kernel<<<4096, 256, 0, stream>>>(xin, co, ln_g + l * NM, ln_b + l * NM, xout);
  }
}

// Round 12
// 151.062 us; speedup vs baseline: 1.0693x; 1.0693x over previous
//
#include <hip/hip_runtime.h>
#include <hip/hip_bf16.h>
#include <math.h>

#define NB 16
#define NS 1024
#define NM 256
#define NH 8
#define NDK 32
#define NL 2

typedef __attribute__((ext_vector_type(4))) float f32x4;
typedef __attribute__((ext_vector_type(8))) short bf16x8;
typedef __attribute__((ext_vector_type(4))) short bf16x4u;

#if __has_builtin(__builtin_amdgcn_exp2f)
#define EXP2F(x) __builtin_amdgcn_exp2f(x)
#else
#define EXP2F(x) exp2f(x)
#endif

__device__ __forceinline__ unsigned short f2bf(float f) {
  unsigned int u = __builtin_bit_cast(unsigned int, f);
  unsigned int r = u + 0x7fffu + ((u >> 16) & 1u);
  return (unsigned short)(r >> 16);
}
__device__ __forceinline__ float bf2f(unsigned short h) {
  unsigned int u = ((unsigned int)h) << 16;
  return __builtin_bit_cast(float, u);
}

// ---------------------------------------------------------------------------
// Pack one int32 0/1 array into a bitmask. inv!=0 packs (v==0).
// SINGLE stream, 16B/lane int4 loads (1KB/wave-load). Wave: 2048 elements in
// 8 iters; per-lane 4-bit nibble -> 32-bit word via 3-level shfl_xor OR.
__global__ __launch_bounds__(256) void packbits_kernel(
    const int* __restrict__ src, unsigned int* __restrict__ dst, int inv)
{
  int wid = blockIdx.x * 4 + (threadIdx.x >> 6);
  int lane = threadIdx.x & 63;
  size_t eb = (size_t)wid * 2048;
  const int4* a4 = (const int4*)(src + eb);
  int lg = lane >> 3;                           // word group 0..7
  int sh = (lane & 7) * 4;                      // nibble position
  unsigned int xo = inv ? 15u : 0u;
#pragma unroll
  for (int k = 0; k < 8; ++k) {
    int4 v = a4[k * 64 + lane];
    unsigned int nc = ((v.x != 0) ? 1u : 0u) | ((v.y != 0) ? 2u : 0u) |
                      ((v.z != 0) ? 4u : 0u) | ((v.w != 0) ? 8u : 0u);
    nc ^= xo;
    unsigned int vc = nc << sh;
    vc |= __shfl_xor(vc, 1, 64);
    vc |= __shfl_xor(vc, 2, 64);
    vc |= __shfl_xor(vc, 4, 64);
    if ((lane & 7) == 0) dst[(size_t)wid * 64 + k * 8 + lg] = vc;
  }
}

// ---------------------------------------------------------------------------
// pkc |= pks (element-wise over the packed words).
__global__ __launch_bounds__(256) void maskcomb_kernel(
    unsigned int* __restrict__ pkc, const unsigned int* __restrict__ pks)
{
  int t = blockIdx.x * 256 + threadIdx.x;
  uint4 a = ((uint4*)pkc)[t];
  uint4 s = ((const uint4*)pks)[t];
  a.x |= s.x; a.y |= s.y; a.z |= s.z; a.w |= s.w;
  ((uint4*)pkc)[t] = a;
}

// ---------------------------------------------------------------------------
// Projection GEMM -> Pt[b][h][d][s] (bf16), 64x64 tile, 4 waves.
__global__ __launch_bounds__(256) void proj_kernel(
    const float* __restrict__ x,        // (B*S, M)
    const float* __restrict__ pw,       // (H, M, DK) this layer
    const float* __restrict__ pb,       // (H*DK)
    unsigned short* __restrict__ Pt)    // (B,H,DK,S)
{
  __shared__ unsigned short As[64][40];
  __shared__ unsigned short Bs[64][40];

  int ct = blockIdx.x;
  int rt = blockIdx.y;
  int t = threadIdx.x;
  int w = t >> 6, lane = t & 63;
  int il = lane & 15, g4 = lane >> 4;
  int wi = w >> 1, wc = w & 1;

  f32x4 acc[2][2] = {};

  int arow = t >> 2, akoff = (t & 3) * 8;
  int bcol = t & 63, bk0 = (t >> 6) * 8;
  int hd = ct * 64 + bcol;
  int h = hd >> 5, d = hd & 31;

  for (int k0 = 0; k0 < NM; k0 += 32) {
    const float* xp = x + (size_t)(rt * 64 + arow) * NM + k0 + akoff;
    f32x4 v0 = *(const f32x4*)xp;
    f32x4 v1 = *(const f32x4*)(xp + 4);
    bf16x8 av;
    av[0] = f2bf(v0[0]); av[1] = f2bf(v0[1]); av[2] = f2bf(v0[2]); av[3] = f2bf(v0[3]);
    av[4] = f2bf(v1[0]); av[5] = f2bf(v1[1]); av[6] = f2bf(v1[2]); av[7] = f2bf(v1[3]);
    *(bf16x8*)&As[arow][akoff] = av;
    const float* wp = pw + (size_t)h * NM * NDK + (size_t)(k0 + bk0) * NDK + d;
    bf16x8 bv;
#pragma unroll
    for (int q = 0; q < 8; ++q) bv[q] = f2bf(wp[q * NDK]);
    *(bf16x8*)&Bs[bcol][bk0] = bv;
    __syncthreads();

    bf16x8 af0 = *(bf16x8*)&As[wi * 32 + il][g4 * 8];
    bf16x8 af1 = *(bf16x8*)&As[wi * 32 + 16 + il][g4 * 8];
    bf16x8 bf0 = *(bf16x8*)&Bs[wc * 32 + il][g4 * 8];
    bf16x8 bf1 = *(bf16x8*)&Bs[wc * 32 + 16 + il][g4 * 8];
    acc[0][0] = __builtin_amdgcn_mfma_f32_16x16x32_bf16(af0, bf0, acc[0][0], 0, 0, 0);
    acc[0][1] = __builtin_amdgcn_mfma_f32_16x16x32_bf16(af0, bf1, acc[0][1], 0, 0, 0);
    acc[1][0] = __builtin_amdgcn_mfma_f32_16x16x32_bf16(af1, bf0, acc[1][0], 0, 0, 0);
    acc[1][1] = __builtin_amdgcn_mfma_f32_16x16x32_bf16(af1, bf1, acc[1][1], 0, 0, 0);
    __syncthreads();
  }

#pragma unroll
  for (int ih = 0; ih < 2; ++ih) {
#pragma unroll
    for (int dh = 0; dh < 2; ++dh) {
      int colhd = ct * 64 + wc * 32 + dh * 16 + il;
      int hh = colhd >> 5, dd = colhd & 31;
      float bias = pb[colhd];
      int r0 = rt * 64 + wi * 32 + ih * 16 + g4 * 4;
      int bb = r0 >> 10, ss = r0 & 1023;
      f32x4 c = acc[ih][dh];
      unsigned short ov[4];
#pragma unroll
      for (int e = 0; e < 4; ++e) ov[e] = f2bf(c[e] + bias);
      size_t idx = ((size_t)(bb * NH + hh) * NDK + dd) * NS + ss;
      *(bf16x4u*)(Pt + idx) = *(bf16x4u*)ov;
    }
  }
}

// ---------------------------------------------------------------------------
// s1 raw (log2e-scaled); s2 factored: s2p = exp2(s2L), s2n = exp2(0.2*s2L).
__global__ __launch_bounds__(256) void s_kernel(
    const unsigned short* __restrict__ Pt,
    const float* __restrict__ aw,   // 64 floats this layer
    const float* __restrict__ abp,  // attn_b + l
    float* __restrict__ s1o, float* __restrict__ s2po, float* __restrict__ s2no)
{
  const float LOG2E = 1.4426950408889634f;
  int t = blockIdx.x * 256 + threadIdx.x;   // (b*H+h)*S + s
  int bh = t >> 10, s = t & 1023;
  const unsigned short* p = Pt + (size_t)bh * NDK * NS + s;
  float s1 = 0.f, s2 = 0.f;
#pragma unroll
  for (int dd = 0; dd < NDK; ++dd) {
    float pv = bf2f(p[dd * NS]);
    s1 += pv * aw[dd];
    s2 += pv * aw[32 + dd];
  }
  float s2L = (s2 + abp[0]) * LOG2E;
  s2L = fminf(fmaxf(s2L, -30.f), 30.f);
  s1o[t] = s1 * LOG2E;
  s2po[t] = EXP2F(s2L);
  s2no[t] = EXP2F(0.2f * s2L);
}

// ---------------------------------------------------------------------------
// Attention, LDS-staged Pt, factored exp with MAX-trick:
//   w = max(e1p*e2p, e1n*e2n)   (== exp2 of LeakyReLU'd score, exactly)
// Block = (b, head, i-quarter): 512 threads = 8 waves; wave w owns 32 rows
// (two 16-row A-fragment groups) -> Pt/table LDS reads amortized 2x.
__global__ __launch_bounds__(512) void attn_kernel(
    const unsigned short* __restrict__ Pt,    // (B,H,DK,S) bf16
    const float* __restrict__ s1a,            // (B,H,S), log2e-scaled
    const float* __restrict__ s2pa,           // exp2(s2L)
    const float* __restrict__ s2na,           // exp2(0.2*s2L)
    const unsigned int* __restrict__ pkc,     // combined mask bits
    const unsigned int* __restrict__ pks,     // smask-only bits
    const int* __restrict__ typep,
    int layer,
    float* __restrict__ co)                   // (B,S,M) f32 concat out
{
  __shared__ __align__(16) unsigned short ptl[32 * 512];  // 32KB, swizzled
  __shared__ float s2pl[1024];                            // 4KB
  __shared__ float s2nl[1024];                            // 4KB

  // XCD chunk swizzle: 64 consecutive logical blocks (2 batches) per XCD.
  int orig = blockIdx.x;
  int lb = (orig & 7) * 64 + (orig >> 3);
  int iq = lb & 3, bh = lb >> 2;
  int b = bh >> 3, h = bh & 7;

  int t = threadIdx.x, w = t >> 6, lane = t & 63;
  int il = lane & 15, g4 = lane >> 4;
  int xorv = (il & 7) << 4;

  const unsigned char* pkb =
      (const unsigned char*)((typep[0] == 1 && layer > 0) ? pks : pkc);
  const unsigned short* ptg = Pt + (size_t)bh * NDK * NS;

  bf16x8 ones;
#pragma unroll
  for (int e = 0; e < 8; ++e) ones[e] = (short)0x3F80;     // bf16 1.0

  int rbase = iq * 256 + w * 32;
  float e1p[2], e1n[2];
  const unsigned char* mrow[2];
#pragma unroll
  for (int g = 0; g < 2; ++g) {
    float s1L = s1a[(size_t)bh * NS + rbase + g * 16 + il];
    s1L = fminf(fmaxf(s1L, -30.f), 30.f);
    e1p[g] = EXP2F(s1L);
    e1n[g] = EXP2F(0.2f * s1L);
    mrow[g] = pkb + (((size_t)(b * NS + rbase + g * 16 + il) * NS) >> 3);
  }

  f32x4 acc[2][2] = {};      // [g][dh]
  f32x4 accd[2] = {};        // [g]

  for (int jh = 0; jh < 2; ++jh) {
    __syncthreads();
    // stage Pt half-slab (32 rows x 512 cols bf16 = 32KB), swizzled
    {
      const char* srcb = (const char*)ptg;
#pragma unroll
      for (int q = 0; q < 4; ++q) {
        int pos = q * 8192 + t * 16;          // 0..32767
        int r = pos >> 10;                    // row 0..31
        int incol = pos & 1023;               // byte within half-row
        uint4 v = *(const uint4*)(srcb + r * 2048 + jh * 1024 + incol);
        *(uint4*)((char*)ptl + r * 1024 + (incol ^ ((r & 7) << 4))) = v;
      }
      if (jh == 0) {
        if (t < 256)
          ((f32x4*)s2pl)[t] = *(const f32x4*)(s2pa + (size_t)bh * NS + t * 4);
        else
          ((f32x4*)s2nl)[t - 256] =
              *(const f32x4*)(s2na + (size_t)bh * NS + (t - 256) * 4);
      }
    }
    __syncthreads();

    for (int jg = 0; jg < 512; jg += 128) {
      uint4 mk0 = *(const uint4*)(mrow[0] + ((jh * 512 + jg) >> 3));
      uint4 mk1 = *(const uint4*)(mrow[1] + ((jh * 512 + jg) >> 3));
#pragma unroll
      for (int s = 0; s < 4; ++s) {
        unsigned int mb0 = ((&mk0.x)[s] >> (g4 * 8)) & 0xFFu;
        unsigned int mb1 = ((&mk1.x)[s] >> (g4 * 8)) & 0xFFu;
        int jl = jg + s * 32 + g4 * 8;                    // local col in half
        int coff = (jl * 2) ^ xorv;
        const char* prow = (const char*)ptl + il * 1024;
        bf16x8 b0 = *(const bf16x8*)(prow + coff);
        bf16x8 b1 = *(const bf16x8*)(prow + 16 * 1024 + coff);
        f32x4 pL = *(const f32x4*)&s2pl[jh * 512 + jl];
        f32x4 pH = *(const f32x4*)&s2pl[jh * 512 + jl + 4];
        f32x4 nL = *(const f32x4*)&s2nl[jh * 512 + jl];
        f32x4 nH = *(const f32x4*)&s2nl[jh * 512 + jl + 4];
        float e2p[8] = {pL[0], pL[1], pL[2], pL[3], pH[0], pH[1], pH[2], pH[3]};
        float e2n[8] = {nL[0], nL[1], nL[2], nL[3], nH[0], nH[1], nH[2], nH[3]};
        bf16x8 af0, af1;
#pragma unroll
        for (int e = 0; e < 8; ++e) {
          float w0 = fmaxf(e1p[0] * e2p[e], e1n[0] * e2n[e]);
          float w1 = fmaxf(e1p[1] * e2p[e], e1n[1] * e2n[e]);
          w0 = (mb0 & (1u << e)) ? 0.f : w0;
          w1 = (mb1 & (1u << e)) ? 0.f : w1;
          af0[e] = (short)__bfloat16_as_ushort(__float2bfloat16(w0));
          af1[e] = (short)__bfloat16_as_ushort(__float2bfloat16(w1));
        }
        acc[0][0] = __builtin_amdgcn_mfma_f32_16x16x32_bf16(af0, b0, acc[0][0], 0, 0, 0);
        acc[0][1] = __builtin_amdgcn_mfma_f32_16x16x32_bf16(af0, b1, acc[0][1], 0, 0, 0);
        accd[0]   = __builtin_amdgcn_mfma_f32_16x16x32_bf16(af0, ones, accd[0], 0, 0, 0);
        acc[1][0] = __builtin_amdgcn_mfma_f32_16x16x32_bf16(af1, b0, acc[1][0], 0, 0, 0);
        acc[1][1] = __builtin_amdgcn_mfma_f32_16x16x32_bf16(af1, b1, acc[1][1], 0, 0, 0);
        accd[1]   = __builtin_amdgcn_mfma_f32_16x16x32_bf16(af1, ones, accd[1], 0, 0, 0);
      }
    }
  }

  // normalize + store concat (D layout: col=il, row=g4*4+e)
#pragma unroll
  for (int g = 0; g < 2; ++g) {
    f32x4 rd;
#pragma unroll
    for (int e = 0; e < 4; ++e) rd[e] = __builtin_amdgcn_rcpf(accd[g][e]);
    float* cob = co + (size_t)(b * NS + rbase + g * 16 + g4 * 4) * NM + h * 32 + il;
#pragma unroll
    for (int e = 0; e < 4; ++e) {
      cob[(size_t)e * NM] = acc[g][0][e] * rd[e];
      cob[(size_t)e * NM + 16] = acc[g][1][e] * rd[e];
    }
  }
}

// ---------------------------------------------------------------------------
// Residual + LayerNorm: row r -> LN(xin[r] + co[r]) * g + b.
__global__ __launch_bounds__(256) void ln_kernel(
    const float* __restrict__ xin, const float* __restrict__ co,
    const float* __restrict__ lng, const float* __restrict__ lnb,
    float* __restrict__ xout)
{
  int row = blockIdx.x * 4 + (threadIdx.x >> 6);
  int lane = threadIdx.x & 63;
  size_t base = (size_t)row * NM + lane * 4;
  f32x4 cv = *(const f32x4*)(co + base);
  f32x4 xv = *(const f32x4*)(xin + base);
  f32x4 r;
#pragma unroll
  for (int e = 0; e < 4; ++e) r[e] = cv[e] + xv[e];
  float sm = r[0] + r[1] + r[2] + r[3];
  float sq = r[0] * r[0] + r[1] * r[1] + r[2] * r[2] + r[3] * r[3];
#pragma unroll
  for (int off = 32; off >= 1; off >>= 1) {
    sm += __shfl_xor(sm, off, 64);
    sq += __shfl_xor(sq, off, 64);
  }
  float mu = sm * (1.f / 256.f);
  float var = sq * (1.f / 256.f) - mu * mu;
  float inv = rsqrtf(var + 1e-5f);
  f32x4 gv = *(const f32x4*)(lng + lane * 4);
  f32x4 bv = *(const f32x4*)(lnb + lane * 4);
  f32x4 o;
#pragma unroll
  for (int e = 0; e < 4; ++e) o[e] = (r[e] - mu) * inv * gv[e] + bv[e];
  *(f32x4*)(xout + base) = o;
}

// ---------------------------------------------------------------------------
extern "C" void kernel_launch(void* const* d_in, const int* in_sizes, int n_in,
                              void* d_out, int out_size, void* d_ws, size_t ws_size,
                              hipStream_t stream)
{
  const int* adj = (const int*)d_in[0];
  const float* inputs = (const float*)d_in[1];
  const int* smask = (const int*)d_in[2];
  const int* typep = (const int*)d_in[3];
  const float* proj_w = (const float*)d_in[4];
  const float* proj_b = (const float*)d_in[5];
  const float* attn_w = (const float*)d_in[6];
  const float* attn_b = (const float*)d_in[7];
  const float* ln_g = (const float*)d_in[8];
  const float* ln_b = (const float*)d_in[9];
  float* out = (float*)d_out;

  char* ws = (char*)d_ws;
  unsigned int* pkc = (unsigned int*)(ws);                      // 2 MB
  unsigned int* pks = (unsigned int*)(ws + (2u << 20));         // 2 MB
  unsigned short* Pt = (unsigned short*)(ws + (4u << 20));      // 8 MB
  float* s1 = (float*)(ws + (12u << 20));                       // 512 KB
  float* s2p = (float*)(ws + (12u << 20) + (1u << 19));         // 512 KB
  float* s2n = (float*)(ws + (13u << 20));                      // 512 KB
  float* x1 = (float*)(ws + (14u << 20));                       // 16 MB
  float* co = out;   // d_out doubles as concat scratch (fully overwritten)

  // Mask packing: single-stream each, 16B/lane loads.
  packbits_kernel<<<2048, 256, 0, stream>>>(adj, pkc, 1);
  packbits_kernel<<<2048, 256, 0, stream>>>(smask, pks, 0);
  maskcomb_kernel<<<512, 256, 0, stream>>>(pkc, pks);

  for (int l = 0; l < NL; ++l) {
    const float* xin = (l == 0) ? inputs : x1;
    float* xout = (l == NL - 1) ? out : x1;
    proj_kernel<<<dim3(4, 256), 256, 0, stream>>>(
        xin, proj_w + (size_t)l * NH * NM * NDK, proj_b + (size_t)l * NH * NDK, Pt);
    s_kernel<<<512, 256, 0, stream>>>(Pt, attn_w + l * 64, attn_b + l, s1, s2p, s2n);
    attn_kernel<<<512, 512, 0, stream>>>(
        Pt, s1, s2p, s2n, pkc, pks, typep, l, co);
    ln_kernel<<<4096, 256, 0, stream>>>(xin, co, ln_g + l * NM, ln_b + l * NM, xout);
  }
}

// Round 13
// 127.964 us; speedup vs baseline: 1.2624x; 1.1805x over previous
//
#include <hip/hip_runtime.h>
#include <hip/hip_bf16.h>
#include <hip/hip_fp16.h>
#include <math.h>

#define NB 16
#define NS 1024
#define NM 256
#define NH 8
#define NDK 32
#define NL 2

typedef __attribute__((ext_vector_type(4))) float f32x4;
typedef __attribute__((ext_vector_type(8))) short bf16x8;
typedef __attribute__((ext_vector_type(4))) short bf16x4u;
typedef __attribute__((ext_vector_type(8))) _Float16 f16x8;
typedef __attribute__((ext_vector_type(2))) _Float16 f16x2;

#if __has_builtin(__builtin_amdgcn_exp2f)
#define EXP2F(x) __builtin_amdgcn_exp2f(x)
#else
#define EXP2F(x) exp2f(x)
#endif

__device__ __forceinline__ unsigned short f2h(float f) {
  _Float16 h = (_Float16)f;
  return __builtin_bit_cast(unsigned short, h);
}
__device__ __forceinline__ float h2f(unsigned short u) {
  return (float)__builtin_bit_cast(_Float16, u);
}

// packed f16 weight word: w2 = max(e1p*e2p, e1n*e2n) & mask (2 elems/op)
__device__ __forceinline__ unsigned int wword(unsigned int pw, unsigned int nw,
                                              f16x2 e1p2, f16x2 e1n2,
                                              unsigned int mk) {
  f16x2 hp = __builtin_bit_cast(f16x2, pw);
  f16x2 hn = __builtin_bit_cast(f16x2, nw);
  f16x2 w = __builtin_elementwise_max(hp * e1p2, hn * e1n2);
  return __builtin_bit_cast(unsigned int, w) & mk;
}

// ---------------------------------------------------------------------------
// Pack one int32 0/1 array into a bitmask. inv!=0 packs (v==0).
__global__ __launch_bounds__(256) void packbits_kernel(
    const int* __restrict__ src, unsigned int* __restrict__ dst, int inv)
{
  int wid = blockIdx.x * 4 + (threadIdx.x >> 6);
  int lane = threadIdx.x & 63;
  size_t eb = (size_t)wid * 2048;
  const int4* a4 = (const int4*)(src + eb);
  int lg = lane >> 3;
  int sh = (lane & 7) * 4;
  unsigned int xo = inv ? 15u : 0u;
#pragma unroll
  for (int k = 0; k < 8; ++k) {
    int4 v = a4[k * 64 + lane];
    unsigned int nc = ((v.x != 0) ? 1u : 0u) | ((v.y != 0) ? 2u : 0u) |
                      ((v.z != 0) ? 4u : 0u) | ((v.w != 0) ? 8u : 0u);
    nc ^= xo;
    unsigned int vc = nc << sh;
    vc |= __shfl_xor(vc, 1, 64);
    vc |= __shfl_xor(vc, 2, 64);
    vc |= __shfl_xor(vc, 4, 64);
    if ((lane & 7) == 0) dst[(size_t)wid * 64 + k * 8 + lg] = vc;
  }
}

// ---------------------------------------------------------------------------
__global__ __launch_bounds__(256) void maskcomb_kernel(
    unsigned int* __restrict__ pkc, const unsigned int* __restrict__ pks)
{
  int t = blockIdx.x * 256 + threadIdx.x;
  uint4 a = ((uint4*)pkc)[t];
  uint4 s = ((const uint4*)pks)[t];
  a.x |= s.x; a.y |= s.y; a.z |= s.z; a.w |= s.w;
  ((uint4*)pkc)[t] = a;
}

// ---------------------------------------------------------------------------
// Projection GEMM -> Pt[b][h][d][s] (f16), 64x64 tile, 4 waves, f16 MFMA.
__global__ __launch_bounds__(256) void proj_kernel(
    const float* __restrict__ x,        // (B*S, M)
    const float* __restrict__ pw,       // (H, M, DK) this layer
    const float* __restrict__ pb,       // (H*DK)
    unsigned short* __restrict__ Pt)    // (B,H,DK,S) f16 bits
{
  __shared__ unsigned short As[64][40];
  __shared__ unsigned short Bs[64][40];

  int ct = blockIdx.x;
  int rt = blockIdx.y;
  int t = threadIdx.x;
  int w = t >> 6, lane = t & 63;
  int il = lane & 15, g4 = lane >> 4;
  int wi = w >> 1, wc = w & 1;

  f32x4 acc[2][2] = {};

  int arow = t >> 2, akoff = (t & 3) * 8;
  int bcol = t & 63, bk0 = (t >> 6) * 8;
  int hd = ct * 64 + bcol;
  int h = hd >> 5, d = hd & 31;

  for (int k0 = 0; k0 < NM; k0 += 32) {
    const float* xp = x + (size_t)(rt * 64 + arow) * NM + k0 + akoff;
    f32x4 v0 = *(const f32x4*)xp;
    f32x4 v1 = *(const f32x4*)(xp + 4);
    unsigned short av[8];
    av[0] = f2h(v0[0]); av[1] = f2h(v0[1]); av[2] = f2h(v0[2]); av[3] = f2h(v0[3]);
    av[4] = f2h(v1[0]); av[5] = f2h(v1[1]); av[6] = f2h(v1[2]); av[7] = f2h(v1[3]);
    *(bf16x8*)&As[arow][akoff] = *(bf16x8*)av;
    const float* wp = pw + (size_t)h * NM * NDK + (size_t)(k0 + bk0) * NDK + d;
    unsigned short bv[8];
#pragma unroll
    for (int q = 0; q < 8; ++q) bv[q] = f2h(wp[q * NDK]);
    *(bf16x8*)&Bs[bcol][bk0] = *(bf16x8*)bv;
    __syncthreads();

    f16x8 af0 = *(f16x8*)&As[wi * 32 + il][g4 * 8];
    f16x8 af1 = *(f16x8*)&As[wi * 32 + 16 + il][g4 * 8];
    f16x8 bf0 = *(f16x8*)&Bs[wc * 32 + il][g4 * 8];
    f16x8 bf1 = *(f16x8*)&Bs[wc * 32 + 16 + il][g4 * 8];
    acc[0][0] = __builtin_amdgcn_mfma_f32_16x16x32_f16(af0, bf0, acc[0][0], 0, 0, 0);
    acc[0][1] = __builtin_amdgcn_mfma_f32_16x16x32_f16(af0, bf1, acc[0][1], 0, 0, 0);
    acc[1][0] = __builtin_amdgcn_mfma_f32_16x16x32_f16(af1, bf0, acc[1][0], 0, 0, 0);
    acc[1][1] = __builtin_amdgcn_mfma_f32_16x16x32_f16(af1, bf1, acc[1][1], 0, 0, 0);
    __syncthreads();
  }

#pragma unroll
  for (int ih = 0; ih < 2; ++ih) {
#pragma unroll
    for (int dh = 0; dh < 2; ++dh) {
      int colhd = ct * 64 + wc * 32 + dh * 16 + il;
      int hh = colhd >> 5, dd = colhd & 31;
      float bias = pb[colhd];
      int r0 = rt * 64 + wi * 32 + ih * 16 + g4 * 4;
      int bb = r0 >> 10, ss = r0 & 1023;
      f32x4 c = acc[ih][dh];
      unsigned short ov[4];
#pragma unroll
      for (int e = 0; e < 4; ++e) ov[e] = f2h(c[e] + bias);
      size_t idx = ((size_t)(bb * NH + hh) * NDK + dd) * NS + ss;
      *(bf16x4u*)(Pt + idx) = *(bf16x4u*)ov;
    }
  }
}

// ---------------------------------------------------------------------------
// s1 raw (log2e-scaled) f32; s2 factored to f16: e2p=exp2(s2L), e2n=exp2(.2 s2L)
__global__ __launch_bounds__(256) void s_kernel(
    const unsigned short* __restrict__ Pt,
    const float* __restrict__ aw,   // 64 floats this layer
    const float* __restrict__ abp,  // attn_b + l
    float* __restrict__ s1o, unsigned short* __restrict__ s2po,
    unsigned short* __restrict__ s2no)
{
  const float LOG2E = 1.4426950408889634f;
  int t = blockIdx.x * 256 + threadIdx.x;   // (b*H+h)*S + s
  int bh = t >> 10, s = t & 1023;
  const unsigned short* p = Pt + (size_t)bh * NDK * NS + s;
  float s1 = 0.f, s2 = 0.f;
#pragma unroll
  for (int dd = 0; dd < NDK; ++dd) {
    float pv = h2f(p[dd * NS]);
    s1 += pv * aw[dd];
    s2 += pv * aw[32 + dd];
  }
  float s2L = (s2 + abp[0]) * LOG2E;
  s2L = fminf(fmaxf(s2L, -7.5f), 7.5f);
  s1o[t] = s1 * LOG2E;
  s2po[t] = f2h(EXP2F(s2L));
  s2no[t] = f2h(EXP2F(0.2f * s2L));
}

// ---------------------------------------------------------------------------
// Attention, LDS-staged f16 Pt, packed-f16 weight math:
//   w2 = pk_max(e1p2*e2p2, e1n2*e2n2) & masktab   (2 elems per VALU op)
// Block = (b, head, i-quarter): 512 threads = 8 waves; wave owns 32 rows.
__global__ __launch_bounds__(512) void attn_kernel(
    const unsigned short* __restrict__ Pt,    // (B,H,DK,S) f16
    const float* __restrict__ s1a,            // (B,H,S), log2e-scaled
    const unsigned short* __restrict__ s2pa,  // f16 exp2(s2L)
    const unsigned short* __restrict__ s2na,  // f16 exp2(0.2*s2L)
    const unsigned int* __restrict__ pkc,     // combined mask bits
    const unsigned int* __restrict__ pks,     // smask-only bits
    const int* __restrict__ typep,
    int layer,
    float* __restrict__ co)                   // (B,S,M) f32 concat out
{
  __shared__ __align__(16) unsigned short ptl[32 * 512];  // 32KB, swizzled
  __shared__ __align__(16) unsigned short e2pl[1024];     // 2KB f16
  __shared__ __align__(16) unsigned short e2nl[1024];     // 2KB f16
  __shared__ uint4 mtab[256];                             // 4KB

  // XCD chunk swizzle: 64 consecutive logical blocks (2 batches) per XCD.
  int orig = blockIdx.x;
  int lb = (orig & 7) * 64 + (orig >> 3);
  int iq = lb & 3, bh = lb >> 2;
  int b = bh >> 3, h = bh & 7;

  int t = threadIdx.x, w = t >> 6, lane = t & 63;
  int il = lane & 15, g4 = lane >> 4;
  int xorv = (il & 7) << 4;

  // mask byte -> 8 f16 AND-masks (bit e set -> halfword e zeroed)
  if (t < 256) {
    unsigned int m = t;
    uint4 e;
    e.x = ((m & 1u)   ? 0u : 0xFFFFu) | ((m & 2u)   ? 0u : 0xFFFF0000u);
    e.y = ((m & 4u)   ? 0u : 0xFFFFu) | ((m & 8u)   ? 0u : 0xFFFF0000u);
    e.z = ((m & 16u)  ? 0u : 0xFFFFu) | ((m & 32u)  ? 0u : 0xFFFF0000u);
    e.w = ((m & 64u)  ? 0u : 0xFFFFu) | ((m & 128u) ? 0u : 0xFFFF0000u);
    mtab[t] = e;
  }

  const unsigned char* pkb =
      (const unsigned char*)((typep[0] == 1 && layer > 0) ? pks : pkc);
  const unsigned short* ptg = Pt + (size_t)bh * NDK * NS;

  f16x8 ones;
#pragma unroll
  for (int e = 0; e < 8; ++e) ones[e] = (_Float16)1.0f;

  int rbase = iq * 256 + w * 32;
  f16x2 e1p2[2], e1n2[2];
  const unsigned char* mrow[2];
#pragma unroll
  for (int g = 0; g < 2; ++g) {
    float s1L = s1a[(size_t)bh * NS + rbase + g * 16 + il];
    s1L = fminf(fmaxf(s1L, -7.5f), 7.5f);
    _Float16 hp = (_Float16)EXP2F(s1L);
    _Float16 hn = (_Float16)EXP2F(0.2f * s1L);
    e1p2[g][0] = hp; e1p2[g][1] = hp;
    e1n2[g][0] = hn; e1n2[g][1] = hn;
    mrow[g] = pkb + (((size_t)(b * NS + rbase + g * 16 + il) * NS) >> 3);
  }

  f32x4 acc[2][2] = {};      // [g][dh]
  f32x4 accd[2] = {};        // [g]

  for (int jh = 0; jh < 2; ++jh) {
    __syncthreads();
    // stage Pt half-slab (32 rows x 512 cols f16 = 32KB), swizzled
    {
      const char* srcb = (const char*)ptg;
#pragma unroll
      for (int q = 0; q < 4; ++q) {
        int pos = q * 8192 + t * 16;          // 0..32767
        int r = pos >> 10;                    // row 0..31
        int incol = pos & 1023;               // byte within half-row
        uint4 v = *(const uint4*)(srcb + r * 2048 + jh * 1024 + incol);
        *(uint4*)((char*)ptl + r * 1024 + (incol ^ ((r & 7) << 4))) = v;
      }
      if (jh == 0) {
        if (t < 128)
          ((uint4*)e2pl)[t] = *(const uint4*)(s2pa + (size_t)bh * NS + t * 8);
        else if (t < 256)
          ((uint4*)e2nl)[t - 128] =
              *(const uint4*)(s2na + (size_t)bh * NS + (t - 128) * 8);
      }
    }
    __syncthreads();

    for (int jg = 0; jg < 512; jg += 128) {
      uint4 mk0 = *(const uint4*)(mrow[0] + ((jh * 512 + jg) >> 3));
      uint4 mk1 = *(const uint4*)(mrow[1] + ((jh * 512 + jg) >> 3));
#pragma unroll
      for (int s = 0; s < 4; ++s) {
        unsigned int mb0 = ((&mk0.x)[s] >> (g4 * 8)) & 0xFFu;
        unsigned int mb1 = ((&mk1.x)[s] >> (g4 * 8)) & 0xFFu;
        uint4 am0 = mtab[mb0];
        uint4 am1 = mtab[mb1];
        int jl = jg + s * 32 + g4 * 8;                    // local col in half
        int coff = (jl * 2) ^ xorv;
        const char* prow = (const char*)ptl + il * 1024;
        f16x8 b0 = *(const f16x8*)(prow + coff);
        f16x8 b1 = *(const f16x8*)(prow + 16 * 1024 + coff);
        int jfull = jh * 512 + jl;
        uint4 p4 = *(const uint4*)&e2pl[jfull];
        uint4 n4 = *(const uint4*)&e2nl[jfull];
        uint4 w0, w1;
        w0.x = wword(p4.x, n4.x, e1p2[0], e1n2[0], am0.x);
        w0.y = wword(p4.y, n4.y, e1p2[0], e1n2[0], am0.y);
        w0.z = wword(p4.z, n4.z, e1p2[0], e1n2[0], am0.z);
        w0.w = wword(p4.w, n4.w, e1p2[0], e1n2[0], am0.w);
        w1.x = wword(p4.x, n4.x, e1p2[1], e1n2[1], am1.x);
        w1.y = wword(p4.y, n4.y, e1p2[1], e1n2[1], am1.y);
        w1.z = wword(p4.z, n4.z, e1p2[1], e1n2[1], am1.z);
        w1.w = wword(p4.w, n4.w, e1p2[1], e1n2[1], am1.w);
        f16x8 af0 = __builtin_bit_cast(f16x8, w0);
        f16x8 af1 = __builtin_bit_cast(f16x8, w1);
        acc[0][0] = __builtin_amdgcn_mfma_f32_16x16x32_f16(af0, b0, acc[0][0], 0, 0, 0);
        acc[0][1] = __builtin_amdgcn_mfma_f32_16x16x32_f16(af0, b1, acc[0][1], 0, 0, 0);
        accd[0]   = __builtin_amdgcn_mfma_f32_16x16x32_f16(af0, ones, accd[0], 0, 0, 0);
        acc[1][0] = __builtin_amdgcn_mfma_f32_16x16x32_f16(af1, b0, acc[1][0], 0, 0, 0);
        acc[1][1] = __builtin_amdgcn_mfma_f32_16x16x32_f16(af1, b1, acc[1][1], 0, 0, 0);
        accd[1]   = __builtin_amdgcn_mfma_f32_16x16x32_f16(af1, ones, accd[1], 0, 0, 0);
      }
    }
  }

  // normalize + store concat (D layout: col=il, row=g4*4+e)
#pragma unroll
  for (int g = 0; g < 2; ++g) {
    f32x4 rd;
#pragma unroll
    for (int e = 0; e < 4; ++e) rd[e] = __builtin_amdgcn_rcpf(accd[g][e]);
    float* cob = co + (size_t)(b * NS + rbase + g * 16 + g4 * 4) * NM + h * 32 + il;
#pragma unroll
    for (int e = 0; e < 4; ++e) {
      cob[(size_t)e * NM] = acc[g][0][e] * rd[e];
      cob[(size_t)e * NM + 16] = acc[g][1][e] * rd[e];
    }
  }
}

// ---------------------------------------------------------------------------
// Residual + LayerNorm: row r -> LN(xin[r] + co[r]) * g + b.
__global__ __launch_bounds__(256) void ln_kernel(
    const float* __restrict__ xin, const float* __restrict__ co,
    const float* __restrict__ lng, const float* __restrict__ lnb,
    float* __restrict__ xout)
{
  int row = blockIdx.x * 4 + (threadIdx.x >> 6);
  int lane = threadIdx.x & 63;
  size_t base = (size_t)row * NM + lane * 4;
  f32x4 cv = *(const f32x4*)(co + base);
  f32x4 xv = *(const f32x4*)(xin + base);
  f32x4 r;
#pragma unroll
  for (int e = 0; e < 4; ++e) r[e] = cv[e] + xv[e];
  float sm = r[0] + r[1] + r[2] + r[3];
  float sq = r[0] * r[0] + r[1] * r[1] + r[2] * r[2] + r[3] * r[3];
#pragma unroll
  for (int off = 32; off >= 1; off >>= 1) {
    sm += __shfl_xor(sm, off, 64);
    sq += __shfl_xor(sq, off, 64);
  }
  float mu = sm * (1.f / 256.f);
  float var = sq * (1.f / 256.f) - mu * mu;
  float inv = rsqrtf(var + 1e-5f);
  f32x4 gv = *(const f32x4*)(lng + lane * 4);
  f32x4 bv = *(const f32x4*)(lnb + lane * 4);
  f32x4 o;
#pragma unroll
  for (int e = 0; e < 4; ++e) o[e] = (r[e] - mu) * inv * gv[e] + bv[e];
  *(f32x4*)(xout + base) = o;
}

// ---------------------------------------------------------------------------
extern "C" void kernel_launch(void* const* d_in, const int* in_sizes, int n_in,
                              void* d_out, int out_size, void* d_ws, size_t ws_size,
                              hipStream_t stream)
{
  const int* adj = (const int*)d_in[0];
  const float* inputs = (const float*)d_in[1];
  const int* smask = (const int*)d_in[2];
  const int* typep = (const int*)d_in[3];
  const float* proj_w = (const float*)d_in[4];
  const float* proj_b = (const float*)d_in[5];
  const float* attn_w = (const float*)d_in[6];
  const float* attn_b = (const float*)d_in[7];
  const float* ln_g = (const float*)d_in[8];
  const float* ln_b = (const float*)d_in[9];
  float* out = (float*)d_out;

  char* ws = (char*)d_ws;
  unsigned int* pkc = (unsigned int*)(ws);                      // 2 MB
  unsigned int* pks = (unsigned int*)(ws + (2u << 20));         // 2 MB
  unsigned short* Pt = (unsigned short*)(ws + (4u << 20));      // 8 MB
  float* s1 = (float*)(ws + (12u << 20));                       // 512 KB
  unsigned short* s2p = (unsigned short*)(ws + (12u << 20) + (1u << 19)); // 256 KB
  unsigned short* s2n = (unsigned short*)(ws + (13u << 20));    // 256 KB
  float* x1 = (float*)(ws + (14u << 20));                       // 16 MB
  float* co = out;   // d_out doubles as concat scratch (fully overwritten)

  packbits_kernel<<<2048, 256, 0, stream>>>(adj, pkc, 1);
  packbits_kernel<<<2048, 256, 0, stream>>>(smask, pks, 0);
  maskcomb_kernel<<<512, 256, 0, stream>>>(pkc, pks);

  for (int l = 0; l < NL; ++l) {
    const float* xin = (l == 0) ? inputs : x1;
    float* xout = (l == NL - 1) ? out : x1;
    proj_kernel<<<dim3(4, 256), 256, 0, stream>>>(
        xin, proj_w + (size_t)l * NH * NM * NDK, proj_b + (size_t)l * NH * NDK, Pt);
    s_kernel<<<512, 256, 0, stream>>>(Pt, attn_w + l * 64, attn_b + l, s1, s2p, s2n);
    attn_kernel<<<512, 512, 0, stream>>>(
        Pt, s1, s2p, s2n, pkc, pks, typep, l, co);
    ln_kernel<<<4096, 256, 0, stream>>>(xin, co, ln_g + l * NM, ln_b + l * NM, xout);
  }
}

// Round 14
// 127.950 us; speedup vs baseline: 1.2625x; 1.0001x over previous
//
#include <hip/hip_runtime.h>
#include <hip/hip_bf16.h>
#include <hip/hip_fp16.h>
#include <math.h>

#define NB 16
#define NS 1024
#define NM 256
#define NH 8
#define NDK 32
#define NL 2

typedef __attribute__((ext_vector_type(4))) float f32x4;
typedef __attribute__((ext_vector_type(8))) short bf16x8;
typedef __attribute__((ext_vector_type(4))) short bf16x4u;
typedef __attribute__((ext_vector_type(8))) _Float16 f16x8;
typedef __attribute__((ext_vector_type(2))) _Float16 f16x2;

#if __has_builtin(__builtin_amdgcn_exp2f)
#define EXP2F(x) __builtin_amdgcn_exp2f(x)
#else
#define EXP2F(x) exp2f(x)
#endif

__device__ __forceinline__ unsigned short f2h(float f) {
  _Float16 h = (_Float16)f;
  return __builtin_bit_cast(unsigned short, h);
}

// packed f16 weight word: w2 = max(e1p*e2p, e1n*e2n) & mask (2 elems/op)
__device__ __forceinline__ unsigned int wword(unsigned int pw, unsigned int nw,
                                              f16x2 e1p2, f16x2 e1n2,
                                              unsigned int mk) {
  f16x2 hp = __builtin_bit_cast(f16x2, pw);
  f16x2 hn = __builtin_bit_cast(f16x2, nw);
  f16x2 w = __builtin_elementwise_max(hp * e1p2, hn * e1n2);
  return __builtin_bit_cast(unsigned int, w) & mk;
}

// ---------------------------------------------------------------------------
// Pack one int32 0/1 array into a bitmask. inv!=0 packs (v==0).
// If orc!=nullptr, also ORs the result into orc (fused maskcomb).
__global__ __launch_bounds__(256) void packbits_kernel(
    const int* __restrict__ src, unsigned int* __restrict__ dst, int inv,
    unsigned int* __restrict__ orc)
{
  int wid = blockIdx.x * 4 + (threadIdx.x >> 6);
  int lane = threadIdx.x & 63;
  size_t eb = (size_t)wid * 2048;
  const int4* a4 = (const int4*)(src + eb);
  int lg = lane >> 3;
  int sh = (lane & 7) * 4;
  unsigned int xo = inv ? 15u : 0u;
#pragma unroll
  for (int k = 0; k < 8; ++k) {
    int4 v = a4[k * 64 + lane];
    unsigned int nc = ((v.x != 0) ? 1u : 0u) | ((v.y != 0) ? 2u : 0u) |
                      ((v.z != 0) ? 4u : 0u) | ((v.w != 0) ? 8u : 0u);
    nc ^= xo;
    unsigned int vc = nc << sh;
    vc |= __shfl_xor(vc, 1, 64);
    vc |= __shfl_xor(vc, 2, 64);
    vc |= __shfl_xor(vc, 4, 64);
    if ((lane & 7) == 0) {
      size_t wi = (size_t)wid * 64 + k * 8 + lg;
      dst[wi] = vc;
      if (orc) orc[wi] |= vc;
    }
  }
}

// ---------------------------------------------------------------------------
// Transpose proj_w (L,H,M,DK) f32 -> Wt (L,H,DK,M) f16. Block = one (l,h).
__global__ __launch_bounds__(256) void wprep_kernel(
    const float* __restrict__ pw, unsigned short* __restrict__ Wt)
{
  __shared__ float lw[256][36];
  int lh = blockIdx.x;                 // 0..15
  int t = threadIdx.x;
  const float* src = pw + (size_t)lh * NM * NDK;
#pragma unroll
  for (int q = 0; q < 8; ++q) {
    int e0 = q * 1024 + t * 4;
    int m = e0 >> 5, dc = e0 & 31;
    f32x4 v = *(const f32x4*)(src + e0);
    *(f32x4*)&lw[m][dc] = v;
  }
  __syncthreads();
  unsigned short* out = Wt + (size_t)lh * NDK * NM;
#pragma unroll
  for (int q = 0; q < 4; ++q) {
    int idx = q * 2048 + t * 8;
    int d = idx >> 8, m = idx & 255;
    unsigned short ov[8];
#pragma unroll
    for (int j = 0; j < 8; ++j) ov[j] = f2h(lw[m + j][d]);
    *(uint4*)(out + (size_t)d * NM + m) = *(uint4*)ov;
  }
}

// ---------------------------------------------------------------------------
// Projection GEMM -> Pt[b][h][d][s] (f16) WITH fused s1/s2 epilogue.
// B from pre-transposed Wt (H,DK,M) f16: coalesced f16x8 loads.
// s1[b,h,s] = P·a1 (log2e-scaled); s2 factored to f16 exp2 tables.
__global__ __launch_bounds__(256) void proj_kernel(
    const float* __restrict__ x,        // (B*S, M)
    const unsigned short* __restrict__ Wt, // (H,DK,M) f16 this layer
    const float* __restrict__ pb,       // (H*DK)
    const float* __restrict__ aw,       // 64 floats this layer
    const float* __restrict__ abp,      // attn_b + l
    unsigned short* __restrict__ Pt,    // (B,H,DK,S) f16
    float* __restrict__ s1o,            // (B,H,S) log2e-scaled
    unsigned short* __restrict__ s2po,  // f16 exp2(s2L)
    unsigned short* __restrict__ s2no)  // f16 exp2(0.2*s2L)
{
  __shared__ unsigned short As[64][40];
  __shared__ unsigned short Bs[64][40];

  const float LOG2E = 1.4426950408889634f;
  int ct = blockIdx.x;
  int rt = blockIdx.y;
  int t = threadIdx.x;
  int w = t >> 6, lane = t & 63;
  int il = lane & 15, g4 = lane >> 4;
  int wi = w >> 1, wc = w & 1;

  f32x4 acc[2][2] = {};

  int arow = t >> 2, akoff = (t & 3) * 8;
  int brow = t >> 2, bkoff = (t & 3) * 8;   // brow = col in tile

  for (int k0 = 0; k0 < NM; k0 += 32) {
    const float* xp = x + (size_t)(rt * 64 + arow) * NM + k0 + akoff;
    f32x4 v0 = *(const f32x4*)xp;
    f32x4 v1 = *(const f32x4*)(xp + 4);
    unsigned short av[8];
    av[0] = f2h(v0[0]); av[1] = f2h(v0[1]); av[2] = f2h(v0[2]); av[3] = f2h(v0[3]);
    av[4] = f2h(v1[0]); av[5] = f2h(v1[1]); av[6] = f2h(v1[2]); av[7] = f2h(v1[3]);
    *(uint4*)&As[arow][akoff] = *(uint4*)av;
    // B: Wt row (ct*64+brow) cols k0+bkoff.. (f16, contiguous)
    uint4 bv = *(const uint4*)(Wt + (size_t)(ct * 64 + brow) * NM + k0 + bkoff);
    *(uint4*)&Bs[brow][bkoff] = bv;
    __syncthreads();

    f16x8 af0 = *(f16x8*)&As[wi * 32 + il][g4 * 8];
    f16x8 af1 = *(f16x8*)&As[wi * 32 + 16 + il][g4 * 8];
    f16x8 bf0 = *(f16x8*)&Bs[wc * 32 + il][g4 * 8];
    f16x8 bf1 = *(f16x8*)&Bs[wc * 32 + 16 + il][g4 * 8];
    acc[0][0] = __builtin_amdgcn_mfma_f32_16x16x32_f16(af0, bf0, acc[0][0], 0, 0, 0);
    acc[0][1] = __builtin_amdgcn_mfma_f32_16x16x32_f16(af0, bf1, acc[0][1], 0, 0, 0);
    acc[1][0] = __builtin_amdgcn_mfma_f32_16x16x32_f16(af1, bf0, acc[1][0], 0, 0, 0);
    acc[1][1] = __builtin_amdgcn_mfma_f32_16x16x32_f16(af1, bf1, acc[1][1], 0, 0, 0);
    __syncthreads();
  }

  // epilogue: write Pt + fused s1/s2 (head = ct*2+wc fixed per wave)
  int head = ct * 2 + wc;
  float a1v[2] = {aw[il], aw[16 + il]};             // aw[d], d = dh*16+il
  float a2v[2] = {aw[32 + il], aw[48 + il]};
  float ab = abp[0];

#pragma unroll
  for (int ih = 0; ih < 2; ++ih) {
    float s1p[4] = {0.f, 0.f, 0.f, 0.f};
    float s2p[4] = {0.f, 0.f, 0.f, 0.f};
    int r0 = rt * 64 + wi * 32 + ih * 16 + g4 * 4;
    int bb = r0 >> 10, ss = r0 & 1023;
#pragma unroll
    for (int dh = 0; dh < 2; ++dh) {
      int colhd = ct * 64 + wc * 32 + dh * 16 + il;
      int dd = colhd & 31;
      float bias = pb[colhd];
      f32x4 c = acc[ih][dh];
      unsigned short ov[4];
#pragma unroll
      for (int e = 0; e < 4; ++e) {
        float Pv = c[e] + bias;
        ov[e] = f2h(Pv);
        s1p[e] += Pv * a1v[dh];
        s2p[e] += Pv * a2v[dh];
      }
      size_t idx = ((size_t)(bb * NH + head) * NDK + dd) * NS + ss;
      *(bf16x4u*)(Pt + idx) = *(bf16x4u*)ov;
    }
    // reduce over il (16 lanes within the g4 group)
#pragma unroll
    for (int e = 0; e < 4; ++e) {
#pragma unroll
      for (int off = 1; off <= 8; off <<= 1) {
        s1p[e] += __shfl_xor(s1p[e], off, 64);
        s2p[e] += __shfl_xor(s2p[e], off, 64);
      }
    }
    if (il == 0) {
      size_t sb = (size_t)(bb * NH + head) * NS + ss;
#pragma unroll
      for (int e = 0; e < 4; ++e) {
        s1o[sb + e] = s1p[e] * LOG2E;
        float s2L = (s2p[e] + ab) * LOG2E;
        s2L = fminf(fmaxf(s2L, -7.5f), 7.5f);
        s2po[sb + e] = f2h(EXP2F(s2L));
        s2no[sb + e] = f2h(EXP2F(0.2f * s2L));
      }
    }
  }
}

// ---------------------------------------------------------------------------
// Attention, LDS-staged f16 Pt, packed-f16 weight math (unchanged from r13).
__global__ __launch_bounds__(512) void attn_kernel(
    const unsigned short* __restrict__ Pt,    // (B,H,DK,S) f16
    const float* __restrict__ s1a,            // (B,H,S), log2e-scaled
    const unsigned short* __restrict__ s2pa,  // f16 exp2(s2L)
    const unsigned short* __restrict__ s2na,  // f16 exp2(0.2*s2L)
    const unsigned int* __restrict__ pkc,     // combined mask bits
    const unsigned int* __restrict__ pks,     // smask-only bits
    const int* __restrict__ typep,
    int layer,
    float* __restrict__ co)                   // (B,S,M) f32 concat out
{
  __shared__ __align__(16) unsigned short ptl[32 * 512];  // 32KB, swizzled
  __shared__ __align__(16) unsigned short e2pl[1024];     // 2KB f16
  __shared__ __align__(16) unsigned short e2nl[1024];     // 2KB f16
  __shared__ uint4 mtab[256];                             // 4KB

  int orig = blockIdx.x;
  int lb = (orig & 7) * 64 + (orig >> 3);
  int iq = lb & 3, bh = lb >> 2;
  int b = bh >> 3, h = bh & 7;

  int t = threadIdx.x, w = t >> 6, lane = t & 63;
  int il = lane & 15, g4 = lane >> 4;
  int xorv = (il & 7) << 4;

  if (t < 256) {
    unsigned int m = t;
    uint4 e;
    e.x = ((m & 1u)   ? 0u : 0xFFFFu) | ((m & 2u)   ? 0u : 0xFFFF0000u);
    e.y = ((m & 4u)   ? 0u : 0xFFFFu) | ((m & 8u)   ? 0u : 0xFFFF0000u);
    e.z = ((m & 16u)  ? 0u : 0xFFFFu) | ((m & 32u)  ? 0u : 0xFFFF0000u);
    e.w = ((m & 64u)  ? 0u : 0xFFFFu) | ((m & 128u) ? 0u : 0xFFFF0000u);
    mtab[t] = e;
  }

  const unsigned char* pkb =
      (const unsigned char*)((typep[0] == 1 && layer > 0) ? pks : pkc);
  const unsigned short* ptg = Pt + (size_t)bh * NDK * NS;

  f16x8 ones;
#pragma unroll
  for (int e = 0; e < 8; ++e) ones[e] = (_Float16)1.0f;

  int rbase = iq * 256 + w * 32;
  f16x2 e1p2[2], e1n2[2];
  const unsigned char* mrow[2];
#pragma unroll
  for (int g = 0; g < 2; ++g) {
    float s1L = s1a[(size_t)bh * NS + rbase + g * 16 + il];
    s1L = fminf(fmaxf(s1L, -7.5f), 7.5f);
    _Float16 hp = (_Float16)EXP2F(s1L);
    _Float16 hn = (_Float16)EXP2F(0.2f * s1L);
    e1p2[g][0] = hp; e1p2[g][1] = hp;
    e1n2[g][0] = hn; e1n2[g][1] = hn;
    mrow[g] = pkb + (((size_t)(b * NS + rbase + g * 16 + il) * NS) >> 3);
  }

  f32x4 acc[2][2] = {};
  f32x4 accd[2] = {};

  for (int jh = 0; jh < 2; ++jh) {
    __syncthreads();
    {
      const char* srcb = (const char*)ptg;
#pragma unroll
      for (int q = 0; q < 4; ++q) {
        int pos = q * 8192 + t * 16;
        int r = pos >> 10;
        int incol = pos & 1023;
        uint4 v = *(const uint4*)(srcb + r * 2048 + jh * 1024 + incol);
        *(uint4*)((char*)ptl + r * 1024 + (incol ^ ((r & 7) << 4))) = v;
      }
      if (jh == 0) {
        if (t < 128)
          ((uint4*)e2pl)[t] = *(const uint4*)(s2pa + (size_t)bh * NS + t * 8);
        else if (t < 256)
          ((uint4*)e2nl)[t - 128] =
              *(const uint4*)(s2na + (size_t)bh * NS + (t - 128) * 8);
      }
    }
    __syncthreads();

    for (int jg = 0; jg < 512; jg += 128) {
      uint4 mk0 = *(const uint4*)(mrow[0] + ((jh * 512 + jg) >> 3));
      uint4 mk1 = *(const uint4*)(mrow[1] + ((jh * 512 + jg) >> 3));
#pragma unroll
      for (int s = 0; s < 4; ++s) {
        unsigned int mb0 = ((&mk0.x)[s] >> (g4 * 8)) & 0xFFu;
        unsigned int mb1 = ((&mk1.x)[s] >> (g4 * 8)) & 0xFFu;
        uint4 am0 = mtab[mb0];
        uint4 am1 = mtab[mb1];
        int jl = jg + s * 32 + g4 * 8;
        int coff = (jl * 2) ^ xorv;
        const char* prow = (const char*)ptl + il * 1024;
        f16x8 b0 = *(const f16x8*)(prow + coff);
        f16x8 b1 = *(const f16x8*)(prow + 16 * 1024 + coff);
        int jfull = jh * 512 + jl;
        uint4 p4 = *(const uint4*)&e2pl[jfull];
        uint4 n4 = *(const uint4*)&e2nl[jfull];
        uint4 w0, w1;
        w0.x = wword(p4.x, n4.x, e1p2[0], e1n2[0], am0.x);
        w0.y = wword(p4.y, n4.y, e1p2[0], e1n2[0], am0.y);
        w0.z = wword(p4.z, n4.z, e1p2[0], e1n2[0], am0.z);
        w0.w = wword(p4.w, n4.w, e1p2[0], e1n2[0], am0.w);
        w1.x = wword(p4.x, n4.x, e1p2[1], e1n2[1], am1.x);
        w1.y = wword(p4.y, n4.y, e1p2[1], e1n2[1], am1.y);
        w1.z = wword(p4.z, n4.z, e1p2[1], e1n2[1], am1.z);
        w1.w = wword(p4.w, n4.w, e1p2[1], e1n2[1], am1.w);
        f16x8 af0 = __builtin_bit_cast(f16x8, w0);
        f16x8 af1 = __builtin_bit_cast(f16x8, w1);
        acc[0][0] = __builtin_amdgcn_mfma_f32_16x16x32_f16(af0, b0, acc[0][0], 0, 0, 0);
        acc[0][1] = __builtin_amdgcn_mfma_f32_16x16x32_f16(af0, b1, acc[0][1], 0, 0, 0);
        accd[0]   = __builtin_amdgcn_mfma_f32_16x16x32_f16(af0, ones, accd[0], 0, 0, 0);
        acc[1][0] = __builtin_amdgcn_mfma_f32_16x16x32_f16(af1, b0, acc[1][0], 0, 0, 0);
        acc[1][1] = __builtin_amdgcn_mfma_f32_16x16x32_f16(af1, b1, acc[1][1], 0, 0, 0);
        accd[1]   = __builtin_amdgcn_mfma_f32_16x16x32_f16(af1, ones, accd[1], 0, 0, 0);
      }
    }
  }

#pragma unroll
  for (int g = 0; g < 2; ++g) {
    f32x4 rd;
#pragma unroll
    for (int e = 0; e < 4; ++e) rd[e] = __builtin_amdgcn_rcpf(accd[g][e]);
    float* cob = co + (size_t)(b * NS + rbase + g * 16 + g4 * 4) * NM + h * 32 + il;
#pragma unroll
    for (int e = 0; e < 4; ++e) {
      cob[(size_t)e * NM] = acc[g][0][e] * rd[e];
      cob[(size_t)e * NM + 16] = acc[g][1][e] * rd[e];
    }
  }
}

// ---------------------------------------------------------------------------
// Residual + LayerNorm: row r -> LN(xin[r] + co[r]) * g + b.
__global__ __launch_bounds__(256) void ln_kernel(
    const float* __restrict__ xin, const float* __restrict__ co,
    const float* __restrict__ lng, const float* __restrict__ lnb,
    float* __restrict__ xout)
{
  int row = blockIdx.x * 4 + (threadIdx.x >> 6);
  int lane = threadIdx.x & 63;
  size_t base = (size_t)row * NM + lane * 4;
  f32x4 cv = *(const f32x4*)(co + base);
  f32x4 xv = *(const f32x4*)(xin + base);
  f32x4 r;
#pragma unroll
  for (int e = 0; e < 4; ++e) r[e] = cv[e] + xv[e];
  float sm = r[0] + r[1] + r[2] + r[3];
  float sq = r[0] * r[0] + r[1] * r[1] + r[2] * r[2] + r[3] * r[3];
#pragma unroll
  for (int off = 32; off >= 1; off >>= 1) {
    sm += __shfl_xor(sm, off, 64);
    sq += __shfl_xor(sq, off, 64);
  }
  float mu = sm * (1.f / 256.f);
  float var = sq * (1.f / 256.f) - mu * mu;
  float inv = rsqrtf(var + 1e-5f);
  f32x4 gv = *(const f32x4*)(lng + lane * 4);
  f32x4 bv = *(const f32x4*)(lnb + lane * 4);
  f32x4 o;
#pragma unroll
  for (int e = 0; e < 4; ++e) o[e] = (r[e] - mu) * inv * gv[e] + bv[e];
  *(f32x4*)(xout + base) = o;
}

// ---------------------------------------------------------------------------
extern "C" void kernel_launch(void* const* d_in, const int* in_sizes, int n_in,
                              void* d_out, int out_size, void* d_ws, size_t ws_size,
                              hipStream_t stream)
{
  const int* adj = (const int*)d_in[0];
  const float* inputs = (const float*)d_in[1];
  const int* smask = (const int*)d_in[2];
  const int* typep = (const int*)d_in[3];
  const float* proj_w = (const float*)d_in[4];
  const float* proj_b = (const float*)d_in[5];
  const float* attn_w = (const float*)d_in[6];
  const float* attn_b = (const float*)d_in[7];
  const float* ln_g = (const float*)d_in[8];
  const float* ln_b = (const float*)d_in[9];
  float* out = (float*)d_out;

  char* ws = (char*)d_ws;
  unsigned int* pkc = (unsigned int*)(ws);                      // 2 MB
  unsigned int* pks = (unsigned int*)(ws + (2u << 20));         // 2 MB
  unsigned short* Pt = (unsigned short*)(ws + (4u << 20));      // 8 MB
  float* s1 = (float*)(ws + (12u << 20));                       // 512 KB
  unsigned short* s2p = (unsigned short*)(ws + (12u << 20) + (1u << 19)); // 256 KB
  unsigned short* s2n = (unsigned short*)(ws + (13u << 20));    // 256 KB
  float* x1 = (float*)(ws + (14u << 20));                       // 16 MB
  unsigned short* Wt = (unsigned short*)(ws + (30u << 20));     // 256 KB
  float* co = out;   // d_out doubles as concat scratch (fully overwritten)

  packbits_kernel<<<2048, 256, 0, stream>>>(adj, pkc, 1, nullptr);
  packbits_kernel<<<2048, 256, 0, stream>>>(smask, pks, 0, pkc);
  wprep_kernel<<<16, 256, 0, stream>>>(proj_w, Wt);

  for (int l = 0; l < NL; ++l) {
    const float* xin = (l == 0) ? inputs : x1;
    float* xout = (l == NL - 1) ? out : x1;
    proj_kernel<<<dim3(4, 256), 256, 0, stream>>>(
        xin, Wt + (size_t)l * NH * NDK * NM, proj_b + (size_t)l * NH * NDK,
        attn_w + l * 64, attn_b + l, Pt, s1, s2p, s2n);
    attn_kernel<<<512, 512, 0, stream>>>(
        Pt, s1, s2p, s2n, pkc, pks, typep, l, co);
    ln_kernel<<<4096, 256, 0, stream>>>(xin, co, ln_g + l * NM, ln_b + l * NM, xout);
  }
}

// Round 15
// 120.193 us; speedup vs baseline: 1.3440x; 1.0645x over previous
//
#include <hip/hip_runtime.h>
#include <hip/hip_bf16.h>
#include <hip/hip_fp16.h>
#include <math.h>

#define NB 16
#define NS 1024
#define NM 256
#define NH 8
#define NDK 32
#define NL 2

typedef __attribute__((ext_vector_type(4))) float f32x4;
typedef __attribute__((ext_vector_type(4))) short bf16x4u;
typedef __attribute__((ext_vector_type(8))) _Float16 f16x8;
typedef __attribute__((ext_vector_type(2))) _Float16 f16x2;

#if __has_builtin(__builtin_amdgcn_exp2f)
#define EXP2F(x) __builtin_amdgcn_exp2f(x)
#else
#define EXP2F(x) exp2f(x)
#endif

__device__ __forceinline__ unsigned short f2h(float f) {
  _Float16 h = (_Float16)f;
  return __builtin_bit_cast(unsigned short, h);
}
__device__ __forceinline__ float h2f(unsigned short u) {
  return (float)__builtin_bit_cast(_Float16, u);
}

// packed f16 weight word: w2 = max(e1p*e2p, e1n*e2n) & mask (2 elems/op)
__device__ __forceinline__ unsigned int wword(unsigned int pw, unsigned int nw,
                                              f16x2 e1p2, f16x2 e1n2,
                                              unsigned int mk) {
  f16x2 hp = __builtin_bit_cast(f16x2, pw);
  f16x2 hn = __builtin_bit_cast(f16x2, nw);
  f16x2 w = __builtin_elementwise_max(hp * e1p2, hn * e1n2);
  return __builtin_bit_cast(unsigned int, w) & mk;
}

// ---------------------------------------------------------------------------
// Transpose proj_w (L,H,M,DK) f32 -> Wt (L,H,DK,M) f16. Block = one (l,h).
__global__ __launch_bounds__(256) void wprep_kernel(
    const float* __restrict__ pw, unsigned short* __restrict__ Wt)
{
  __shared__ float lw[256][36];
  int lh = blockIdx.x;                 // 0..15
  int t = threadIdx.x;
  const float* src = pw + (size_t)lh * NM * NDK;
#pragma unroll
  for (int q = 0; q < 8; ++q) {
    int e0 = q * 1024 + t * 4;
    int m = e0 >> 5, dc = e0 & 31;
    f32x4 v = *(const f32x4*)(src + e0);
    *(f32x4*)&lw[m][dc] = v;
  }
  __syncthreads();
  unsigned short* out = Wt + (size_t)lh * NDK * NM;
#pragma unroll
  for (int q = 0; q < 4; ++q) {
    int idx = q * 2048 + t * 8;
    int d = idx >> 8, m = idx & 255;
    unsigned short ov[8];
#pragma unroll
    for (int j = 0; j < 8; ++j) ov[j] = f2h(lw[m + j][d]);
    *(uint4*)(out + (size_t)d * NM + m) = *(uint4*)ov;
  }
}

// ---------------------------------------------------------------------------
// Projection GEMM body -> Pt[b][h][d][s] (f16) + fused s1/s2 epilogue.
__device__ __forceinline__ void proj_body(
    int ct, int rt, int t,
    const float* __restrict__ x, const unsigned short* __restrict__ Wt,
    const float* __restrict__ pb, const float* __restrict__ aw,
    const float* __restrict__ abp,
    unsigned short* __restrict__ Pt, float* __restrict__ s1o,
    unsigned short* __restrict__ s2po, unsigned short* __restrict__ s2no,
    unsigned short (*As)[40], unsigned short (*Bs)[40])
{
  const float LOG2E = 1.4426950408889634f;
  int w = t >> 6, lane = t & 63;
  int il = lane & 15, g4 = lane >> 4;
  int wi = w >> 1, wc = w & 1;

  f32x4 acc[2][2] = {};
  int arow = t >> 2, akoff = (t & 3) * 8;

  for (int k0 = 0; k0 < NM; k0 += 32) {
    const float* xp = x + (size_t)(rt * 64 + arow) * NM + k0 + akoff;
    f32x4 v0 = *(const f32x4*)xp;
    f32x4 v1 = *(const f32x4*)(xp + 4);
    unsigned short av[8];
    av[0] = f2h(v0[0]); av[1] = f2h(v0[1]); av[2] = f2h(v0[2]); av[3] = f2h(v0[3]);
    av[4] = f2h(v1[0]); av[5] = f2h(v1[1]); av[6] = f2h(v1[2]); av[7] = f2h(v1[3]);
    *(uint4*)&As[arow][akoff] = *(uint4*)av;
    uint4 bv = *(const uint4*)(Wt + (size_t)(ct * 64 + arow) * NM + k0 + akoff);
    *(uint4*)&Bs[arow][akoff] = bv;
    __syncthreads();

    f16x8 af0 = *(f16x8*)&As[wi * 32 + il][g4 * 8];
    f16x8 af1 = *(f16x8*)&As[wi * 32 + 16 + il][g4 * 8];
    f16x8 bf0 = *(f16x8*)&Bs[wc * 32 + il][g4 * 8];
    f16x8 bf1 = *(f16x8*)&Bs[wc * 32 + 16 + il][g4 * 8];
    acc[0][0] = __builtin_amdgcn_mfma_f32_16x16x32_f16(af0, bf0, acc[0][0], 0, 0, 0);
    acc[0][1] = __builtin_amdgcn_mfma_f32_16x16x32_f16(af0, bf1, acc[0][1], 0, 0, 0);
    acc[1][0] = __builtin_amdgcn_mfma_f32_16x16x32_f16(af1, bf0, acc[1][0], 0, 0, 0);
    acc[1][1] = __builtin_amdgcn_mfma_f32_16x16x32_f16(af1, bf1, acc[1][1], 0, 0, 0);
    __syncthreads();
  }

  int head = ct * 2 + wc;
  float a1v[2] = {aw[il], aw[16 + il]};
  float a2v[2] = {aw[32 + il], aw[48 + il]};
  float ab = abp[0];

#pragma unroll
  for (int ih = 0; ih < 2; ++ih) {
    float s1p[4] = {0.f, 0.f, 0.f, 0.f};
    float s2p[4] = {0.f, 0.f, 0.f, 0.f};
    int r0 = rt * 64 + wi * 32 + ih * 16 + g4 * 4;
    int bb = r0 >> 10, ss = r0 & 1023;
#pragma unroll
    for (int dh = 0; dh < 2; ++dh) {
      int colhd = ct * 64 + wc * 32 + dh * 16 + il;
      int dd = colhd & 31;
      float bias = pb[colhd];
      f32x4 c = acc[ih][dh];
      unsigned short ov[4];
#pragma unroll
      for (int e = 0; e < 4; ++e) {
        float Pv = c[e] + bias;
        ov[e] = f2h(Pv);
        s1p[e] += Pv * a1v[dh];
        s2p[e] += Pv * a2v[dh];
      }
      size_t idx = ((size_t)(bb * NH + head) * NDK + dd) * NS + ss;
      *(bf16x4u*)(Pt + idx) = *(bf16x4u*)ov;
    }
#pragma unroll
    for (int e = 0; e < 4; ++e) {
#pragma unroll
      for (int off = 1; off <= 8; off <<= 1) {
        s1p[e] += __shfl_xor(s1p[e], off, 64);
        s2p[e] += __shfl_xor(s2p[e], off, 64);
      }
    }
    if (il == 0) {
      size_t sb = (size_t)(bb * NH + head) * NS + ss;
#pragma unroll
      for (int e = 0; e < 4; ++e) {
        s1o[sb + e] = s1p[e] * LOG2E;
        float s2L = (s2p[e] + ab) * LOG2E;
        s2L = fminf(fmaxf(s2L, -7.5f), 7.5f);
        s2po[sb + e] = f2h(EXP2F(s2L));
        s2no[sb + e] = f2h(EXP2F(0.2f * s2L));
      }
    }
  }
}

// ---------------------------------------------------------------------------
// Fused prelude: blocks [0,2048) pack adj==0 bits -> pka; [2048,4096) pack
// smask bits -> pks; [4096,5120) proj layer 0. All overlap on the device.
__global__ __launch_bounds__(256) void prelude_kernel(
    const int* __restrict__ adj, const int* __restrict__ smask,
    unsigned int* __restrict__ pka, unsigned int* __restrict__ pks,
    const float* __restrict__ x, const unsigned short* __restrict__ Wt0,
    const float* __restrict__ pb0, const float* __restrict__ aw0,
    const float* __restrict__ ab0,
    unsigned short* __restrict__ Pt, float* __restrict__ s1o,
    unsigned short* __restrict__ s2po, unsigned short* __restrict__ s2no)
{
  __shared__ unsigned short As[64][40];
  __shared__ unsigned short Bs[64][40];

  int bid = blockIdx.x;
  int t = threadIdx.x;
  if (bid < 4096) {
    const int* src = (bid < 2048) ? adj : smask;
    unsigned int* dst = (bid < 2048) ? pka : pks;
    unsigned int xo = (bid < 2048) ? 15u : 0u;
    int wid = (bid & 2047) * 4 + (t >> 6);
    int lane = t & 63;
    size_t eb = (size_t)wid * 2048;
    const int4* a4 = (const int4*)(src + eb);
    int lg = lane >> 3;
    int sh = (lane & 7) * 4;
#pragma unroll
    for (int k = 0; k < 8; ++k) {
      int4 v = a4[k * 64 + lane];
      unsigned int nc = ((v.x != 0) ? 1u : 0u) | ((v.y != 0) ? 2u : 0u) |
                        ((v.z != 0) ? 4u : 0u) | ((v.w != 0) ? 8u : 0u);
      nc ^= xo;
      unsigned int vc = nc << sh;
      vc |= __shfl_xor(vc, 1, 64);
      vc |= __shfl_xor(vc, 2, 64);
      vc |= __shfl_xor(vc, 4, 64);
      if ((lane & 7) == 0) dst[(size_t)wid * 64 + k * 8 + lg] = vc;
    }
  } else {
    int pb2 = bid - 4096;
    proj_body(pb2 & 3, pb2 >> 2, t, x, Wt0, pb0, aw0, ab0,
              Pt, s1o, s2po, s2no, As, Bs);
  }
}

// ---------------------------------------------------------------------------
// Standalone proj (layer 1).
__global__ __launch_bounds__(256) void proj_kernel(
    const float* __restrict__ x, const unsigned short* __restrict__ Wt,
    const float* __restrict__ pb, const float* __restrict__ aw,
    const float* __restrict__ abp,
    unsigned short* __restrict__ Pt, float* __restrict__ s1o,
    unsigned short* __restrict__ s2po, unsigned short* __restrict__ s2no)
{
  __shared__ unsigned short As[64][40];
  __shared__ unsigned short Bs[64][40];
  proj_body(blockIdx.x, blockIdx.y, threadIdx.x, x, Wt, pb, aw, abp,
            Pt, s1o, s2po, s2no, As, Bs);
}

// ---------------------------------------------------------------------------
// Attention, LDS-staged f16 Pt, packed-f16 weight math. Mask = (pka|pks) or
// pks-only (selected by pointing pka_eff at pks — OR is idempotent).
__global__ __launch_bounds__(512) void attn_kernel(
    const unsigned short* __restrict__ Pt,    // (B,H,DK,S) f16
    const float* __restrict__ s1a,            // (B,H,S), log2e-scaled
    const unsigned short* __restrict__ s2pa,  // f16 exp2(s2L)
    const unsigned short* __restrict__ s2na,  // f16 exp2(0.2*s2L)
    const unsigned int* __restrict__ pka,     // adj==0 bits
    const unsigned int* __restrict__ pks,     // smask bits
    const int* __restrict__ typep,
    int layer,
    unsigned short* __restrict__ co)          // (B,S,M) f16 concat out
{
  __shared__ __align__(16) unsigned short ptl[32 * 512];  // 32KB, swizzled
  __shared__ __align__(16) unsigned short e2pl[1024];     // 2KB f16
  __shared__ __align__(16) unsigned short e2nl[1024];     // 2KB f16
  __shared__ uint4 mtab[256];                             // 4KB

  int orig = blockIdx.x;
  int lb = (orig & 7) * 64 + (orig >> 3);
  int iq = lb & 3, bh = lb >> 2;
  int b = bh >> 3, h = bh & 7;

  int t = threadIdx.x, w = t >> 6, lane = t & 63;
  int il = lane & 15, g4 = lane >> 4;
  int xorv = (il & 7) << 4;

  if (t < 256) {
    unsigned int m = t;
    uint4 e;
    e.x = ((m & 1u)   ? 0u : 0xFFFFu) | ((m & 2u)   ? 0u : 0xFFFF0000u);
    e.y = ((m & 4u)   ? 0u : 0xFFFFu) | ((m & 8u)   ? 0u : 0xFFFF0000u);
    e.z = ((m & 16u)  ? 0u : 0xFFFFu) | ((m & 32u)  ? 0u : 0xFFFF0000u);
    e.w = ((m & 64u)  ? 0u : 0xFFFFu) | ((m & 128u) ? 0u : 0xFFFF0000u);
    mtab[t] = e;
  }

  bool comb = !(typep[0] == 1 && layer > 0);
  const unsigned char* pa = (const unsigned char*)(comb ? pka : pks);
  const unsigned char* ps = (const unsigned char*)pks;
  const unsigned short* ptg = Pt + (size_t)bh * NDK * NS;

  f16x8 ones;
#pragma unroll
  for (int e = 0; e < 8; ++e) ones[e] = (_Float16)1.0f;

  int rbase = iq * 256 + w * 32;
  f16x2 e1p2[2], e1n2[2];
  size_t mbyte[2];
#pragma unroll
  for (int g = 0; g < 2; ++g) {
    float s1L = s1a[(size_t)bh * NS + rbase + g * 16 + il];
    s1L = fminf(fmaxf(s1L, -7.5f), 7.5f);
    _Float16 hp = (_Float16)EXP2F(s1L);
    _Float16 hn = (_Float16)EXP2F(0.2f * s1L);
    e1p2[g][0] = hp; e1p2[g][1] = hp;
    e1n2[g][0] = hn; e1n2[g][1] = hn;
    mbyte[g] = ((size_t)(b * NS + rbase + g * 16 + il) * NS) >> 3;
  }

  f32x4 acc[2][2] = {};
  f32x4 accd[2] = {};

  for (int jh = 0; jh < 2; ++jh) {
    __syncthreads();
    {
      const char* srcb = (const char*)ptg;
#pragma unroll
      for (int q = 0; q < 4; ++q) {
        int pos = q * 8192 + t * 16;
        int r = pos >> 10;
        int incol = pos & 1023;
        uint4 v = *(const uint4*)(srcb + r * 2048 + jh * 1024 + incol);
        *(uint4*)((char*)ptl + r * 1024 + (incol ^ ((r & 7) << 4))) = v;
      }
      if (jh == 0) {
        if (t < 128)
          ((uint4*)e2pl)[t] = *(const uint4*)(s2pa + (size_t)bh * NS + t * 8);
        else if (t < 256)
          ((uint4*)e2nl)[t - 128] =
              *(const uint4*)(s2na + (size_t)bh * NS + (t - 128) * 8);
      }
    }
    __syncthreads();

    for (int jg = 0; jg < 512; jg += 128) {
      size_t off = (size_t)((jh * 512 + jg) >> 3);
      uint4 ka0 = *(const uint4*)(pa + mbyte[0] + off);
      uint4 ks0 = *(const uint4*)(ps + mbyte[0] + off);
      uint4 ka1 = *(const uint4*)(pa + mbyte[1] + off);
      uint4 ks1 = *(const uint4*)(ps + mbyte[1] + off);
      uint4 mk0, mk1;
      mk0.x = ka0.x | ks0.x; mk0.y = ka0.y | ks0.y;
      mk0.z = ka0.z | ks0.z; mk0.w = ka0.w | ks0.w;
      mk1.x = ka1.x | ks1.x; mk1.y = ka1.y | ks1.y;
      mk1.z = ka1.z | ks1.z; mk1.w = ka1.w | ks1.w;
#pragma unroll
      for (int s = 0; s < 4; ++s) {
        unsigned int mb0 = ((&mk0.x)[s] >> (g4 * 8)) & 0xFFu;
        unsigned int mb1 = ((&mk1.x)[s] >> (g4 * 8)) & 0xFFu;
        uint4 am0 = mtab[mb0];
        uint4 am1 = mtab[mb1];
        int jl = jg + s * 32 + g4 * 8;
        int coff = (jl * 2) ^ xorv;
        const char* prow = (const char*)ptl + il * 1024;
        f16x8 b0 = *(const f16x8*)(prow + coff);
        f16x8 b1 = *(const f16x8*)(prow + 16 * 1024 + coff);
        int jfull = jh * 512 + jl;
        uint4 p4 = *(const uint4*)&e2pl[jfull];
        uint4 n4 = *(const uint4*)&e2nl[jfull];
        uint4 w0, w1;
        w0.x = wword(p4.x, n4.x, e1p2[0], e1n2[0], am0.x);
        w0.y = wword(p4.y, n4.y, e1p2[0], e1n2[0], am0.y);
        w0.z = wword(p4.z, n4.z, e1p2[0], e1n2[0], am0.z);
        w0.w = wword(p4.w, n4.w, e1p2[0], e1n2[0], am0.w);
        w1.x = wword(p4.x, n4.x, e1p2[1], e1n2[1], am1.x);
        w1.y = wword(p4.y, n4.y, e1p2[1], e1n2[1], am1.y);
        w1.z = wword(p4.z, n4.z, e1p2[1], e1n2[1], am1.z);
        w1.w = wword(p4.w, n4.w, e1p2[1], e1n2[1], am1.w);
        f16x8 af0 = __builtin_bit_cast(f16x8, w0);
        f16x8 af1 = __builtin_bit_cast(f16x8, w1);
        acc[0][0] = __builtin_amdgcn_mfma_f32_16x16x32_f16(af0, b0, acc[0][0], 0, 0, 0);
        acc[0][1] = __builtin_amdgcn_mfma_f32_16x16x32_f16(af0, b1, acc[0][1], 0, 0, 0);
        accd[0]   = __builtin_amdgcn_mfma_f32_16x16x32_f16(af0, ones, accd[0], 0, 0, 0);
        acc[1][0] = __builtin_amdgcn_mfma_f32_16x16x32_f16(af1, b0, acc[1][0], 0, 0, 0);
        acc[1][1] = __builtin_amdgcn_mfma_f32_16x16x32_f16(af1, b1, acc[1][1], 0, 0, 0);
        accd[1]   = __builtin_amdgcn_mfma_f32_16x16x32_f16(af1, ones, accd[1], 0, 0, 0);
      }
    }
  }

#pragma unroll
  for (int g = 0; g < 2; ++g) {
    f32x4 rd;
#pragma unroll
    for (int e = 0; e < 4; ++e) rd[e] = __builtin_amdgcn_rcpf(accd[g][e]);
    unsigned short* cob =
        co + (size_t)(b * NS + rbase + g * 16 + g4 * 4) * NM + h * 32 + il;
#pragma unroll
    for (int e = 0; e < 4; ++e) {
      cob[(size_t)e * NM] = f2h(acc[g][0][e] * rd[e]);
      cob[(size_t)e * NM + 16] = f2h(acc[g][1][e] * rd[e]);
    }
  }
}

// ---------------------------------------------------------------------------
// Residual + LayerNorm: row r -> LN(xin[r] + co[r]) * g + b.  co is f16.
__global__ __launch_bounds__(256) void ln_kernel(
    const float* __restrict__ xin, const unsigned short* __restrict__ co,
    const float* __restrict__ lng, const float* __restrict__ lnb,
    float* __restrict__ xout)
{
  int row = blockIdx.x * 4 + (threadIdx.x >> 6);
  int lane = threadIdx.x & 63;
  size_t base = (size_t)row * NM + lane * 4;
  ushort4 cv = *(const ushort4*)(co + base);
  f32x4 xv = *(const f32x4*)(xin + base);
  f32x4 r;
  r[0] = xv[0] + h2f(cv.x);
  r[1] = xv[1] + h2f(cv.y);
  r[2] = xv[2] + h2f(cv.z);
  r[3] = xv[3] + h2f(cv.w);
  float sm = r[0] + r[1] + r[2] + r[3];
  float sq = r[0] * r[0] + r[1] * r[1] + r[2] * r[2] + r[3] * r[3];
#pragma unroll
  for (int off = 32; off >= 1; off >>= 1) {
    sm += __shfl_xor(sm, off, 64);
    sq += __shfl_xor(sq, off, 64);
  }
  float mu = sm * (1.f / 256.f);
  float var = sq * (1.f / 256.f) - mu * mu;
  float inv = rsqrtf(var + 1e-5f);
  f32x4 gv = *(const f32x4*)(lng + lane * 4);
  f32x4 bv = *(const f32x4*)(lnb + lane * 4);
  f32x4 o;
#pragma unroll
  for (int e = 0; e < 4; ++e) o[e] = (r[e] - mu) * inv * gv[e] + bv[e];
  *(f32x4*)(xout + base) = o;
}

// ---------------------------------------------------------------------------
extern "C" void kernel_launch(void* const* d_in, const int* in_sizes, int n_in,
                              void* d_out, int out_size, void* d_ws, size_t ws_size,
                              hipStream_t stream)
{
  const int* adj = (const int*)d_in[0];
  const float* inputs = (const float*)d_in[1];
  const int* smask = (const int*)d_in[2];
  const int* typep = (const int*)d_in[3];
  const float* proj_w = (const float*)d_in[4];
  const float* proj_b = (const float*)d_in[5];
  const float* attn_w = (const float*)d_in[6];
  const float* attn_b = (const float*)d_in[7];
  const float* ln_g = (const float*)d_in[8];
  const float* ln_b = (const float*)d_in[9];
  float* out = (float*)d_out;

  char* ws = (char*)d_ws;
  unsigned int* pka = (unsigned int*)(ws);                      // 2 MB
  unsigned int* pks = (unsigned int*)(ws + (2u << 20));         // 2 MB
  unsigned short* Pt = (unsigned short*)(ws + (4u << 20));      // 8 MB
  float* s1 = (float*)(ws + (12u << 20));                       // 512 KB
  unsigned short* s2p = (unsigned short*)(ws + (12u << 20) + (1u << 19)); // 256 KB
  unsigned short* s2n = (unsigned short*)(ws + (13u << 20));    // 256 KB
  float* x1 = (float*)(ws + (14u << 20));                       // 16 MB
  unsigned short* Wt = (unsigned short*)(ws + (30u << 20));     // 256 KB
  unsigned short* co = (unsigned short*)(ws + (31u << 20));     // 8 MB f16

  wprep_kernel<<<16, 256, 0, stream>>>(proj_w, Wt);
  // Layer 0: mask packing overlapped with projection in one grid.
  prelude_kernel<<<5120, 256, 0, stream>>>(
      adj, smask, pka, pks, inputs, Wt, proj_b, attn_w, attn_b,
      Pt, s1, s2p, s2n);
  attn_kernel<<<512, 512, 0, stream>>>(
      Pt, s1, s2p, s2n, pka, pks, typep, 0, co);
  ln_kernel<<<4096, 256, 0, stream>>>(inputs, co, ln_g, ln_b, x1);
  // Layer 1.
  proj_kernel<<<dim3(4, 256), 256, 0, stream>>>(
      x1, Wt + (size_t)NH * NDK * NM, proj_b + (size_t)NH * NDK,
      attn_w + 64, attn_b + 1, Pt, s1, s2p, s2n);
  attn_kernel<<<512, 512, 0, stream>>>(
      Pt, s1, s2p, s2n, pka, pks, typep, 1, co);
  ln_kernel<<<4096, 256, 0, stream>>>(x1, co, ln_g + NM, ln_b + NM, out);
}